// Round 2
// baseline (2308.171 us; speedup 1.0000x reference)
//
#include <hip/hip_runtime.h>
#include <cmath>

typedef __bf16 bf16_t;
typedef __bf16 bf16x8 __attribute__((ext_vector_type(8)));
typedef float  f32x4  __attribute__((ext_vector_type(4)));

#define SLEN 2048
#define DMOD 2048
#define NHQ  32
#define NHKV 4
#define HD   128
#define NQC  4096
#define NKVC 512
#define NQKVC 5120
#define NEXP 8
#define NF   768

// ---------------- helpers ----------------
__device__ __forceinline__ float wredsum(float v) {
#pragma unroll
  for (int off = 32; off > 0; off >>= 1) v += __shfl_xor(v, off);
  return v;
}

// ---------------- rope table (fp64 for accuracy) ----------------
__global__ void rope_table_k(float* __restrict__ cosT, float* __restrict__ sinT) {
  int idx = blockIdx.x * 256 + threadIdx.x;
  if (idx >= SLEN * 64) return;
  int t = idx >> 6, j = idx & 63;
  double inv = exp(-0.2158673524681918 * (double)j);  // ln(1e6)/64
  double ang = (double)t * inv;
  cosT[idx] = (float)cos(ang);
  sinT[idx] = (float)sin(ang);
}

// ---------------- weight transpose: fp32 [R][C] -> bf16 hi/lo pair [C][R] ----------------
__global__ __launch_bounds__(256) void transpose_split2_k(const float* __restrict__ in,
                                                          bf16_t* __restrict__ outH,
                                                          bf16_t* __restrict__ outL,
                                                          int R, int C) {
  __shared__ float tile[32][33];
  int tx = threadIdx.x, ty = threadIdx.y;
  int c0 = blockIdx.x * 32, r0 = blockIdx.y * 32;
#pragma unroll
  for (int i = 0; i < 4; i++)
    tile[ty + i * 8][tx] = in[(size_t)(r0 + ty + i * 8) * C + c0 + tx];
  __syncthreads();
#pragma unroll
  for (int i = 0; i < 4; i++) {
    int c = c0 + ty + i * 8;
    int r = r0 + tx;
    float w = tile[tx][ty + i * 8];
    bf16_t hi = (bf16_t)w;
    bf16_t lo = (bf16_t)(w - (float)hi);
    size_t o = (size_t)c * R + r;
    outH[o] = hi;
    outL[o] = lo;
  }
}

// ---------------- plain transpose: fp32 [b][R][C] -> bf16 [b][C][R] ----------------
__global__ __launch_bounds__(256) void transpose_plain_k(const float* __restrict__ in,
                                                         bf16_t* __restrict__ out,
                                                         int R, int C) {
  __shared__ float tile[32][33];
  int b = blockIdx.z;
  const float* inb = in + (size_t)b * R * C;
  bf16_t* outb = out + (size_t)b * R * C;
  int tx = threadIdx.x, ty = threadIdx.y;
  int c0 = blockIdx.x * 32, r0 = blockIdx.y * 32;
#pragma unroll
  for (int i = 0; i < 4; i++)
    tile[ty + i * 8][tx] = inb[(size_t)(r0 + ty + i * 8) * C + c0 + tx];
  __syncthreads();
#pragma unroll
  for (int i = 0; i < 4; i++) {
    int c = c0 + ty + i * 8;
    int r = r0 + tx;
    outb[(size_t)c * R + r] = (bf16_t)tile[tx][ty + i * 8];
  }
}

// ---------------- rmsnorm1: fp32 row -> bf16 hi/lo pair [t][2048] ----------------
__global__ __launch_bounds__(256) void rmsnorm1_k(const float* __restrict__ hs,
                                                  const float* __restrict__ sc,
                                                  bf16_t* __restrict__ xnH,
                                                  bf16_t* __restrict__ xnL) {
  const int t = blockIdx.x;
  const float* row = hs + (size_t)t * DMOD;
  const int tid = threadIdx.x;
  const int i0 = tid * 8;
  float4 a = *(const float4*)(row + i0);
  float4 b = *(const float4*)(row + i0 + 4);
  float x[8] = {a.x, a.y, a.z, a.w, b.x, b.y, b.z, b.w};
  float ss = 0.f;
#pragma unroll
  for (int j = 0; j < 8; j++) ss += x[j] * x[j];
  ss = wredsum(ss);
  __shared__ float red[4];
  if ((tid & 63) == 0) red[tid >> 6] = ss;
  __syncthreads();
  float rn = rsqrtf((red[0] + red[1] + red[2] + red[3]) * (1.f / 2048.f) + 1e-6f);
#pragma unroll
  for (int j = 0; j < 8; j++) {
    float v = x[j] * rn * sc[i0 + j];
    bf16_t hi = (bf16_t)v;
    bf16_t lo = (bf16_t)(v - (float)hi);
    xnH[(size_t)t * DMOD + i0 + j] = hi;
    xnL[(size_t)t * DMOD + i0 + j] = lo;
  }
}

// ---------------- fused split MFMA GEMM core ----------------
// C[64x64] = (Ahi+Alo)*(Bhi+Blo)^T approx: hi*hi + lo*hi + hi*lo.
// 256 threads, 4 waves; wave w owns rows w*16..; 16x16x32 MFMA.
// A-frag A[m=lane&15][k=quad*8+j]; B-frag Bt[n=lane&15][k=quad*8+j];
// C/D: row=quad*4+reg, col=lane&15.
template <class AHI, class ALO>
__device__ __forceinline__ void gemm_split_core(AHI getAh, ALO getAl,
                                                const bf16_t* __restrict__ Bh,
                                                const bf16_t* __restrict__ Bl,
                                                int ldb, int n0, int K, f32x4 acc[4]) {
  __shared__ bf16_t AsH[64][32], AsL[64][32], BsH[64][32], BsL[64][32];
  const int t = threadIdx.x;
  const int wave = t >> 6, lane = t & 63;
  const int m16 = lane & 15, quad = lane >> 4;
  const int sr = t >> 2, sc = (t & 3) << 3;
  const bf16_t* __restrict__ ah = getAh(sr);
  const bf16_t* __restrict__ al = getAl(sr);
  const bf16_t* __restrict__ bh = Bh + (size_t)(n0 + sr) * ldb;
  const bf16_t* __restrict__ bl = Bl + (size_t)(n0 + sr) * ldb;
  for (int k0 = 0; k0 < K; k0 += 32) {
    __syncthreads();
    *(uint4*)(&AsH[sr][sc]) = *(const uint4*)(ah + k0 + sc);
    *(uint4*)(&AsL[sr][sc]) = *(const uint4*)(al + k0 + sc);
    *(uint4*)(&BsH[sr][sc]) = *(const uint4*)(bh + k0 + sc);
    *(uint4*)(&BsL[sr][sc]) = *(const uint4*)(bl + k0 + sc);
    __syncthreads();
    bf16x8 afh = *(const bf16x8*)(&AsH[wave * 16 + m16][quad * 8]);
    bf16x8 afl = *(const bf16x8*)(&AsL[wave * 16 + m16][quad * 8]);
#pragma unroll
    for (int nt = 0; nt < 4; nt++) {
      bf16x8 bfh = *(const bf16x8*)(&BsH[nt * 16 + m16][quad * 8]);
      bf16x8 bfl = *(const bf16x8*)(&BsL[nt * 16 + m16][quad * 8]);
      acc[nt] = __builtin_amdgcn_mfma_f32_16x16x32_bf16(afh, bfh, acc[nt], 0, 0, 0);
      acc[nt] = __builtin_amdgcn_mfma_f32_16x16x32_bf16(afl, bfh, acc[nt], 0, 0, 0);
      acc[nt] = __builtin_amdgcn_mfma_f32_16x16x32_bf16(afh, bfl, acc[nt], 0, 0, 0);
    }
  }
}

__global__ __launch_bounds__(256) void gemm_split_plain_k(const bf16_t* __restrict__ Ah,
                                                          const bf16_t* __restrict__ Al,
                                                          int lda,
                                                          const bf16_t* __restrict__ Bh,
                                                          const bf16_t* __restrict__ Bl,
                                                          int ldb, int K,
                                                          float* __restrict__ C, int ldc) {
  const int m0 = blockIdx.y * 64, n0 = blockIdx.x * 64;
  f32x4 zz = {0.f, 0.f, 0.f, 0.f};
  f32x4 acc[4] = {zz, zz, zz, zz};
  gemm_split_core([=](int r) { return Ah + (size_t)(m0 + r) * lda; },
                  [=](int r) { return Al + (size_t)(m0 + r) * lda; },
                  Bh, Bl, ldb, n0, K, acc);
  const int t = threadIdx.x, wave = t >> 6, lane = t & 63;
  const int m16 = lane & 15, quad = lane >> 4;
  const int mb = m0 + wave * 16 + quad * 4;
  const int nb = n0 + m16;
#pragma unroll
  for (int nt = 0; nt < 4; nt++)
#pragma unroll
    for (int r = 0; r < 4; r++)
      C[(size_t)(mb + r) * ldc + nb + nt * 16] = acc[nt][r];
}

__global__ __launch_bounds__(256) void gemm_split_resid_k(const bf16_t* __restrict__ Ah,
                                                          const bf16_t* __restrict__ Al,
                                                          int lda,
                                                          const bf16_t* __restrict__ Bh,
                                                          const bf16_t* __restrict__ Bl,
                                                          int ldb, int K,
                                                          const float* __restrict__ resid,
                                                          float* __restrict__ C, int ldc) {
  const int m0 = blockIdx.y * 64, n0 = blockIdx.x * 64;
  f32x4 zz = {0.f, 0.f, 0.f, 0.f};
  f32x4 acc[4] = {zz, zz, zz, zz};
  gemm_split_core([=](int r) { return Ah + (size_t)(m0 + r) * lda; },
                  [=](int r) { return Al + (size_t)(m0 + r) * lda; },
                  Bh, Bl, ldb, n0, K, acc);
  const int t = threadIdx.x, wave = t >> 6, lane = t & 63;
  const int m16 = lane & 15, quad = lane >> 4;
  const int mb = m0 + wave * 16 + quad * 4;
  const int nb = n0 + m16;
#pragma unroll
  for (int nt = 0; nt < 4; nt++)
#pragma unroll
    for (int r = 0; r < 4; r++) {
      size_t idx = (size_t)(mb + r) * ldc + nb + nt * 16;
      C[idx] = acc[nt][r] + resid[idx];
    }
}

// ---------------- plain MFMA GEMM core (MoE, bf16 single) ----------------
template <class AROW>
__device__ __forceinline__ void gemm_core(AROW getA, const bf16_t* __restrict__ Bt, int ldb,
                                          int n0, int K, f32x4 acc[4]) {
  __shared__ bf16_t As[64][32];
  __shared__ bf16_t Bs[64][32];
  const int t = threadIdx.x;
  const int wave = t >> 6, lane = t & 63;
  const int m16 = lane & 15, quad = lane >> 4;
  const int sr = t >> 2, sc = (t & 3) << 3;
  const bf16_t* __restrict__ arow = getA(sr);
  const bf16_t* __restrict__ brow = Bt + (size_t)(n0 + sr) * ldb;
  for (int k0 = 0; k0 < K; k0 += 32) {
    __syncthreads();
    *(uint4*)(&As[sr][sc]) = *(const uint4*)(arow + k0 + sc);
    *(uint4*)(&Bs[sr][sc]) = *(const uint4*)(brow + k0 + sc);
    __syncthreads();
    bf16x8 af = *(const bf16x8*)(&As[wave * 16 + m16][quad * 8]);
#pragma unroll
    for (int nt = 0; nt < 4; nt++) {
      bf16x8 bfr = *(const bf16x8*)(&Bs[nt * 16 + m16][quad * 8]);
      acc[nt] = __builtin_amdgcn_mfma_f32_16x16x32_bf16(af, bfr, acc[nt], 0, 0, 0);
    }
  }
}

// ---------------- qk-norm + rope, IN-PLACE on fp32 qkv ----------------
__global__ __launch_bounds__(128) void qknorm_rope_k(float* __restrict__ qkv,
                                                     const float* __restrict__ qsc,
                                                     const float* __restrict__ ksc,
                                                     const float* __restrict__ cosT,
                                                     const float* __restrict__ sinT) {
  const int t = blockIdx.x;
  const int hh = blockIdx.y;  // 0..31 q heads, 32..35 k heads
  const bool isq = hh < NHQ;
  float* ptr = qkv + (size_t)t * NQKVC + (isq ? hh * HD : NQC + (hh - NHQ) * HD);
  const int i = threadIdx.x;
  float x = ptr[i];
  float ss = x * x;
  ss = wredsum(ss);
  __shared__ float red2[2];
  __shared__ float xs[128];
  if ((i & 63) == 0) red2[i >> 6] = ss;
  __syncthreads();
  float rn = rsqrtf((red2[0] + red2[1]) * (1.f / 128.f) + 1e-6f);
  float xn = x * rn * (isq ? qsc[i] : ksc[i]);
  xs[i] = xn;
  __syncthreads();
  int j = i & 63;
  float c = cosT[t * 64 + j];
  float s = sinT[t * 64 + j];
  float rot = (i < 64) ? -xs[i + 64] : xs[i - 64];
  ptr[i] = xn * c + rot * s;
}

// ---------------- fp32 flash attention, 32-row q tiles ----------------
__global__ __launch_bounds__(256) void attn_k(const float* __restrict__ qkv,
                                              bf16_t* __restrict__ attnH,
                                              bf16_t* __restrict__ attnL) {
  const int qb = blockIdx.x;       // 0..63
  const int hh = blockIdx.y;       // 0..31
  const int hk = hh >> 3;
  __shared__ float Qs[32][132], Ks[32][132], Vs[32][128], Ps[32][36];
  __shared__ float mS[32], lS[32], aS[32];
  const int t = threadIdx.x;
  {  // load Q tile
    int r = t >> 3, cb = (t & 7) * 16;
    const float* src = qkv + (size_t)(qb * 32 + r) * NQKVC + hh * HD + cb;
#pragma unroll
    for (int i = 0; i < 4; i++)
      *(float4*)&Qs[r][cb + i * 4] = *(const float4*)(src + i * 4);
  }
  if (t < 32) { mS[t] = -1e30f; lS[t] = 0.f; }
  float O[16];
#pragma unroll
  for (int i = 0; i < 16; i++) O[i] = 0.f;
  const int tr = t >> 4, tc = t & 15;
  const int r8 = t >> 3, cg = t & 7;
  const float SCALE = 0.08838834764831845f;  // 1/sqrt(128)
  for (int kb = 0; kb <= qb; kb++) {
    __syncthreads();
    {  // load K,V tiles
      int r = t >> 3, cb = (t & 7) * 16;
      const float* ksrc = qkv + (size_t)(kb * 32 + r) * NQKVC + NQC + hk * HD + cb;
      const float* vsrc = qkv + (size_t)(kb * 32 + r) * NQKVC + (NQC + NKVC) + hk * HD + cb;
#pragma unroll
      for (int i = 0; i < 4; i++) {
        *(float4*)&Ks[r][cb + i * 4] = *(const float4*)(ksrc + i * 4);
        *(float4*)&Vs[r][cb + i * 4] = *(const float4*)(vsrc + i * 4);
      }
    }
    __syncthreads();
    // scores: rows {2tr, 2tr+1}, cols {tc, tc+16}
    float s00 = 0.f, s01 = 0.f, s10 = 0.f, s11 = 0.f;
#pragma unroll 8
    for (int d = 0; d < 128; d += 4) {
      float4 qa = *(const float4*)&Qs[2 * tr][d];
      float4 qc = *(const float4*)&Qs[2 * tr + 1][d];
      float4 ka = *(const float4*)&Ks[tc][d];
      float4 kc = *(const float4*)&Ks[tc + 16][d];
      s00 += qa.x * ka.x + qa.y * ka.y + qa.z * ka.z + qa.w * ka.w;
      s01 += qa.x * kc.x + qa.y * kc.y + qa.z * kc.z + qa.w * kc.w;
      s10 += qc.x * ka.x + qc.y * ka.y + qc.z * ka.z + qc.w * ka.w;
      s11 += qc.x * kc.x + qc.y * kc.y + qc.z * kc.z + qc.w * kc.w;
    }
    float sv0[2] = {s00, s10};
    float sv1[2] = {s01, s11};
    const int col0 = kb * 32 + tc, col1 = col0 + 16;
#pragma unroll
    for (int rr = 0; rr < 2; rr++) {
      int row = 2 * tr + rr;
      int qrow = qb * 32 + row;
      float x0 = (col0 <= qrow) ? sv0[rr] * SCALE : -1e30f;
      float x1 = (col1 <= qrow) ? sv1[rr] * SCALE : -1e30f;
      float mx = fmaxf(x0, x1);
#pragma unroll
      for (int off = 1; off < 16; off <<= 1) mx = fmaxf(mx, __shfl_xor(mx, off));
      float mo = mS[row];
      float mn = fmaxf(mo, mx);
      float p0 = __expf(x0 - mn), p1 = __expf(x1 - mn);
      float psum = p0 + p1;
#pragma unroll
      for (int off = 1; off < 16; off <<= 1) psum += __shfl_xor(psum, off);
      if (tc == 0) {
        float al = __expf(mo - mn);
        aS[row] = al;
        lS[row] = lS[row] * al + psum;
        mS[row] = mn;
      }
      Ps[row][tc] = p0;
      Ps[row][tc + 16] = p1;
    }
    __syncthreads();
    // PV: thread owns row r8, col chunks i4*32 + cg*4
    float al = aS[r8];
#pragma unroll
    for (int i = 0; i < 16; i++) O[i] *= al;
    for (int j = 0; j < 32; j++) {
      float p = Ps[r8][j];
#pragma unroll
      for (int i4 = 0; i4 < 4; i4++) {
        float4 v4 = *(const float4*)&Vs[j][i4 * 32 + cg * 4];
        O[i4 * 4 + 0] = fmaf(p, v4.x, O[i4 * 4 + 0]);
        O[i4 * 4 + 1] = fmaf(p, v4.y, O[i4 * 4 + 1]);
        O[i4 * 4 + 2] = fmaf(p, v4.z, O[i4 * 4 + 2]);
        O[i4 * 4 + 3] = fmaf(p, v4.w, O[i4 * 4 + 3]);
      }
    }
  }
  __syncthreads();
  float linv = 1.f / lS[r8];
  size_t rowoff = (size_t)(qb * 32 + r8) * NQC + hh * HD;
#pragma unroll
  for (int i4 = 0; i4 < 4; i4++)
#pragma unroll
    for (int jj = 0; jj < 4; jj++) {
      float v = O[i4 * 4 + jj] * linv;
      bf16_t hi = (bf16_t)v;
      bf16_t lo = (bf16_t)(v - (float)hi);
      int col = i4 * 32 + cg * 4 + jj;
      attnH[rowoff + col] = hi;
      attnL[rowoff + col] = lo;
    }
}

// ---------------- rmsnorm2 + router logits (fp32, deterministic) ----------------
__global__ __launch_bounds__(256) void rmsnorm2_router_k(const float* __restrict__ hid,
                                                         const float* __restrict__ sc2,
                                                         const float* __restrict__ rW,
                                                         bf16_t* __restrict__ xf,
                                                         float* __restrict__ rlog) {
  const int t = blockIdx.x;
  const float* row = hid + (size_t)t * DMOD;
  const int tid = threadIdx.x;
  const int i0 = tid * 8;
  float4 a = *(const float4*)(row + i0);
  float4 b = *(const float4*)(row + i0 + 4);
  float x[8] = {a.x, a.y, a.z, a.w, b.x, b.y, b.z, b.w};
  float ss = 0.f;
#pragma unroll
  for (int j = 0; j < 8; j++) ss += x[j] * x[j];
  ss = wredsum(ss);
  __shared__ float red[4];
  if ((tid & 63) == 0) red[tid >> 6] = ss;
  __syncthreads();
  float rn = rsqrtf((red[0] + red[1] + red[2] + red[3]) * (1.f / 2048.f) + 1e-6f);
  float acc[8];
#pragma unroll
  for (int e = 0; e < 8; e++) acc[e] = 0.f;
#pragma unroll
  for (int j = 0; j < 8; j++) {
    float xn = x[j] * rn * sc2[i0 + j];
    xf[(size_t)t * DMOD + i0 + j] = (bf16_t)xn;
    const float* w = rW + (size_t)(i0 + j) * NEXP;
#pragma unroll
    for (int e = 0; e < 8; e++) acc[e] += xn * w[e];
  }
#pragma unroll
  for (int e = 0; e < 8; e++) acc[e] = wredsum(acc[e]);
  __shared__ float wacc[4][8];
  if ((tid & 63) == 0)
#pragma unroll
    for (int e = 0; e < 8; e++) wacc[tid >> 6][e] = acc[e];
  __syncthreads();
  if (tid < 8) rlog[t * NEXP + tid] = wacc[0][tid] + wacc[1][tid] + wacc[2][tid] + wacc[3][tid];
}

// ---------------- top-2 selection + gates; aux_loss == 1.0 analytically ----------------
__global__ void topk_k(const float* __restrict__ rlog, int* __restrict__ sel,
                       float* __restrict__ gates, float* __restrict__ aux) {
  int t = blockIdx.x * 256 + threadIdx.x;
  if (t == 0) aux[0] = 1.0f;
  if (t >= SLEN) return;
  const float* l = rlog + t * NEXP;
  int i1 = 0; float v1 = l[0];
#pragma unroll
  for (int e = 1; e < 8; e++) if (l[e] > v1) { v1 = l[e]; i1 = e; }
  int i2 = -1; float v2 = -1e30f;
#pragma unroll
  for (int e = 0; e < 8; e++) if (e != i1 && l[e] > v2) { v2 = l[e]; i2 = e; }
  float e21 = expf(v2 - v1);
  float inv = 1.f / (1.f + e21);
  sel[t * 2 + 0] = i1;
  sel[t * 2 + 1] = i2;
  gates[t * 2 + 0] = inv;
  gates[t * 2 + 1] = e21 * inv;
}

// ---------------- scatter tokens to per-expert lists ----------------
__global__ void scatter_k(const int* __restrict__ sel, const float* __restrict__ gates,
                          int* __restrict__ cnt, int* __restrict__ tok,
                          float* __restrict__ gateL) {
  int i = blockIdx.x * 256 + threadIdx.x;
  if (i >= SLEN * 2) return;
  int e = sel[i];
  int pos = atomicAdd(&cnt[e], 1);
  tok[e * SLEN + pos] = i >> 1;
  gateL[e * SLEN + pos] = gates[i];
}

// ---------------- MoE up-GEMM (gathered rows, silu+bias epilogue, bf16 out) ----------------
__global__ __launch_bounds__(256) void gemm_up_k(const bf16_t* __restrict__ xf,
                                                 const bf16_t* __restrict__ upWT,
                                                 const int* __restrict__ cnt,
                                                 const int* __restrict__ tok,
                                                 const float* __restrict__ up_b,
                                                 bf16_t* __restrict__ hbuf) {
  const int e = blockIdx.z;
  const int c = cnt[e];
  const int m0 = blockIdx.y * 64;
  if (m0 >= c) return;
  const int n0 = blockIdx.x * 64;
  const int* tokE = tok + e * SLEN;
  const bf16_t* BtE = upWT + (size_t)e * NF * DMOD;
  f32x4 zz = {0.f, 0.f, 0.f, 0.f};
  f32x4 acc[4] = {zz, zz, zz, zz};
  gemm_core([=](int r) {
      int s = m0 + r; if (s >= c) s = c - 1;
      return xf + (size_t)tokE[s] * DMOD;
    }, BtE, DMOD, n0, DMOD, acc);
  const int t = threadIdx.x, wave = t >> 6, lane = t & 63;
  const int m16 = lane & 15, quad = lane >> 4;
  const int mb = m0 + wave * 16 + quad * 4;
  const int nb = n0 + m16;
#pragma unroll
  for (int nt = 0; nt < 4; nt++)
#pragma unroll
    for (int r = 0; r < 4; r++) {
      int slot = mb + r;
      if (slot < c) {
        int n = nb + nt * 16;
        float x = acc[nt][r] + up_b[e * NF + n];
        float v = x / (1.f + __expf(-x));
        hbuf[((size_t)e * SLEN + slot) * NF + n] = (bf16_t)v;
      }
    }
}

// ---------------- MoE down-GEMM (bias + gate, atomicAdd into final hidden) ----------------
__global__ __launch_bounds__(256) void gemm_down_k(const bf16_t* __restrict__ hbuf,
                                                   const bf16_t* __restrict__ downWT,
                                                   const int* __restrict__ cnt,
                                                   const int* __restrict__ tok,
                                                   const float* __restrict__ gateL,
                                                   const float* __restrict__ down_b,
                                                   float* __restrict__ outH) {
  const int e = blockIdx.z;
  const int c = cnt[e];
  const int m0 = blockIdx.y * 64;
  if (m0 >= c) return;
  const int n0 = blockIdx.x * 64;
  const bf16_t* Ah = hbuf + (size_t)e * SLEN * NF;
  const bf16_t* BtE = downWT + (size_t)e * DMOD * NF;
  f32x4 zz = {0.f, 0.f, 0.f, 0.f};
  f32x4 acc[4] = {zz, zz, zz, zz};
  gemm_core([=](int r) { return Ah + (size_t)(m0 + r) * NF; }, BtE, NF, n0, NF, acc);
  const int t = threadIdx.x, wave = t >> 6, lane = t & 63;
  const int m16 = lane & 15, quad = lane >> 4;
  const int mb = m0 + wave * 16 + quad * 4;
  const int nb = n0 + m16;
#pragma unroll
  for (int nt = 0; nt < 4; nt++)
#pragma unroll
    for (int r = 0; r < 4; r++) {
      int slot = mb + r;
      if (slot < c) {
        int n = nb + nt * 16;
        int tk = tok[e * SLEN + slot];
        float g = gateL[e * SLEN + slot];
        atomicAdd(&outH[(size_t)tk * DMOD + n], g * (acc[nt][r] + down_b[e * DMOD + n]));
      }
    }
}

// ---------------- host ----------------
extern "C" void kernel_launch(void* const* d_in, const int* in_sizes, int n_in,
                              void* d_out, int out_size, void* d_ws, size_t ws_size,
                              hipStream_t stream) {
  (void)in_sizes; (void)n_in; (void)out_size;
  const float* hs   = (const float*)d_in[0];
  const float* ln1  = (const float*)d_in[1];
  const float* ln2  = (const float*)d_in[2];
  const float* Wq   = (const float*)d_in[3];
  const float* Wk   = (const float*)d_in[4];
  const float* Wv   = (const float*)d_in[5];
  const float* Wo   = (const float*)d_in[6];
  const float* qns  = (const float*)d_in[7];
  const float* kns  = (const float*)d_in[8];
  const float* rW   = (const float*)d_in[9];
  const float* upW  = (const float*)d_in[10];
  const float* upB  = (const float*)d_in[11];
  const float* dnW  = (const float*)d_in[12];
  const float* dnB  = (const float*)d_in[13];
  float* dout = (float*)d_out;

  // ---- workspace layout with lifetime overlays (total ~135.5 MB) ----
  // A (41,943,040): Bqkv hi|lo [5120][2048] -> attn hi|lo [2048][4096] -> upWT
  // B (33,554,432): Wo hi|lo [2048][4096]   -> hbuf [8][2048][768]
  // C (16,777,216): xn hi|lo [2048][2048]   -> xf bf16 [2048][2048]
  // D (41,943,040): qkv fp32 [2048][5120]   -> downWT [8][2048][768]
  // E (~1.2 MB):    cos/sin/sel/gates/cnt/tok/gateL
  const size_t NEED = 135431168ull;
  if (ws_size < NEED) return;  // clean failure (zeros) instead of OOB crash
  char* ws = (char*)d_ws;
  const size_t OA = 0;
  const size_t OB = OA + 41943040ull;
  const size_t OC = OB + 33554432ull;
  const size_t OD = OC + 16777216ull;
  const size_t OE = OD + 41943040ull;

  bf16_t* BqkvH  = (bf16_t*)(ws + OA);
  bf16_t* BqkvL  = (bf16_t*)(ws + OA + 20971520ull);
  bf16_t* attnH  = (bf16_t*)(ws + OA);
  bf16_t* attnL  = (bf16_t*)(ws + OA + 16777216ull);
  bf16_t* upWT   = (bf16_t*)(ws + OA);
  bf16_t* WoH    = (bf16_t*)(ws + OB);
  bf16_t* WoL    = (bf16_t*)(ws + OB + 16777216ull);
  bf16_t* hbuf   = (bf16_t*)(ws + OB);
  bf16_t* xnH    = (bf16_t*)(ws + OC);
  bf16_t* xnL    = (bf16_t*)(ws + OC + 8388608ull);
  bf16_t* xf     = (bf16_t*)(ws + OC);
  float*  qkv    = (float*)(ws + OD);
  bf16_t* downWT = (bf16_t*)(ws + OD);
  float*  cosT   = (float*)(ws + OE);
  float*  sinT   = (float*)(ws + OE + 524288ull);
  int*    sel    = (int*)(ws + OE + 1048576ull);
  float*  gates  = (float*)(ws + OE + 1064960ull);
  int*    cnt    = (int*)(ws + OE + 1081344ull);
  int*    tok    = (int*)(ws + OE + 1082368ull);
  float*  gateL  = (float*)(ws + OE + 1147904ull);

  hipMemsetAsync(cnt, 0, 1024, stream);
  rope_table_k<<<512, 256, 0, stream>>>(cosT, sinT);

  dim3 tb(32, 8);
  // Wq [2048][4096] -> rows 0..4095 of Bqkv; Wk -> 4096..4607; Wv -> 4608..5119
  transpose_split2_k<<<dim3(128, 64), tb, 0, stream>>>(Wq, BqkvH, BqkvL, 2048, 4096);
  transpose_split2_k<<<dim3(16, 64), tb, 0, stream>>>(Wk, BqkvH + (size_t)4096 * 2048,
                                                      BqkvL + (size_t)4096 * 2048, 2048, 512);
  transpose_split2_k<<<dim3(16, 64), tb, 0, stream>>>(Wv, BqkvH + (size_t)4608 * 2048,
                                                      BqkvL + (size_t)4608 * 2048, 2048, 512);
  transpose_split2_k<<<dim3(64, 128), tb, 0, stream>>>(Wo, WoH, WoL, 4096, 2048);

  rmsnorm1_k<<<2048, 256, 0, stream>>>(hs, ln1, xnH, xnL);
  gemm_split_plain_k<<<dim3(80, 32), 256, 0, stream>>>(xnH, xnL, 2048, BqkvH, BqkvL, 2048,
                                                       2048, qkv, NQKVC);
  qknorm_rope_k<<<dim3(2048, 36), 128, 0, stream>>>(qkv, qns, kns, cosT, sinT);
  attn_k<<<dim3(64, 32), 256, 0, stream>>>(qkv, attnH, attnL);
  gemm_split_resid_k<<<dim3(32, 32), 256, 0, stream>>>(attnH, attnL, 4096, WoH, WoL, 4096,
                                                       4096, hs, dout, DMOD);

  rmsnorm2_router_k<<<2048, 256, 0, stream>>>(dout, ln2, rW, xf, dout + 4194304);
  topk_k<<<8, 256, 0, stream>>>(dout + 4194304, sel, gates, dout + 4210688);
  scatter_k<<<16, 256, 0, stream>>>(sel, gates, cnt, tok, gateL);

  // up/down weight transposes go into regions freed after the Wo GEMM / attention
  transpose_plain_k<<<dim3(24, 64, 8), tb, 0, stream>>>(upW, upWT, 2048, 768);
  transpose_plain_k<<<dim3(64, 24, 8), tb, 0, stream>>>(dnW, downWT, 768, 2048);

  gemm_up_k<<<dim3(12, 32, 8), 256, 0, stream>>>(xf, upWT, cnt, tok, upB, hbuf);
  gemm_down_k<<<dim3(32, 32, 8), 256, 0, stream>>>(hbuf, downWT, cnt, tok, gateL, dnB, dout);
}

// Round 5
// 1220.062 us; speedup vs baseline: 1.8918x; 1.8918x over previous
//
#include <hip/hip_runtime.h>
#include <cmath>

typedef __bf16 bf16_t;
typedef __bf16 bf16x8 __attribute__((ext_vector_type(8)));
typedef __bf16 bf16x4 __attribute__((ext_vector_type(4)));
typedef float  f32x4  __attribute__((ext_vector_type(4)));

#define SLEN 2048
#define DMOD 2048
#define NHQ  32
#define NHKV 4
#define HD   128
#define NQC  4096
#define NKVC 512
#define NQKVC 5120
#define NEXP 8
#define NF   768

// LDS strides for attention tiles. Rules: inner dim must hold the FULL tile
// extent (K tile is [kv=64][d=128] -> stride >= 128!), and stride must be a
// multiple of 8 elements (16 B) so bf16x8 ds_read_b128 stays aligned.
// KSTR=136 (d-stride for sK: 128+8). VSTR/PSTR=72 (kv-stride: 64+8).
#define KSTR 136
#define VSTR 72
#define PSTR 72

// ---------------- helpers ----------------
__device__ __forceinline__ float wredsum(float v) {
#pragma unroll
  for (int off = 32; off > 0; off >>= 1) v += __shfl_xor(v, off);
  return v;
}

// ---------------- rope table (fp64 for accuracy) ----------------
__global__ void rope_table_k(float* __restrict__ cosT, float* __restrict__ sinT) {
  int idx = blockIdx.x * 256 + threadIdx.x;
  if (idx >= SLEN * 64) return;
  int t = idx >> 6, j = idx & 63;
  double inv = exp(-0.2158673524681918 * (double)j);  // ln(1e6)/64
  double ang = (double)t * inv;
  cosT[idx] = (float)cos(ang);
  sinT[idx] = (float)sin(ang);
}

// ---------------- weight transpose: fp32 [R][C] -> bf16 hi/lo pair [C][R] ----------------
__global__ __launch_bounds__(256) void transpose_split2_k(const float* __restrict__ in,
                                                          bf16_t* __restrict__ outH,
                                                          bf16_t* __restrict__ outL,
                                                          int R, int C) {
  __shared__ float tile[32][33];
  int tx = threadIdx.x, ty = threadIdx.y;
  int c0 = blockIdx.x * 32, r0 = blockIdx.y * 32;
#pragma unroll
  for (int i = 0; i < 4; i++)
    tile[ty + i * 8][tx] = in[(size_t)(r0 + ty + i * 8) * C + c0 + tx];
  __syncthreads();
#pragma unroll
  for (int i = 0; i < 4; i++) {
    int c = c0 + ty + i * 8;
    int r = r0 + tx;
    float w = tile[tx][ty + i * 8];
    bf16_t hi = (bf16_t)w;
    bf16_t lo = (bf16_t)(w - (float)hi);
    size_t o = (size_t)c * R + r;
    outH[o] = hi;
    outL[o] = lo;
  }
}

// ---------------- plain transpose: fp32 [b][R][C] -> bf16 [b][C][R] ----------------
__global__ __launch_bounds__(256) void transpose_plain_k(const float* __restrict__ in,
                                                         bf16_t* __restrict__ out,
                                                         int R, int C) {
  __shared__ float tile[32][33];
  int b = blockIdx.z;
  const float* inb = in + (size_t)b * R * C;
  bf16_t* outb = out + (size_t)b * R * C;
  int tx = threadIdx.x, ty = threadIdx.y;
  int c0 = blockIdx.x * 32, r0 = blockIdx.y * 32;
#pragma unroll
  for (int i = 0; i < 4; i++)
    tile[ty + i * 8][tx] = inb[(size_t)(r0 + ty + i * 8) * C + c0 + tx];
  __syncthreads();
#pragma unroll
  for (int i = 0; i < 4; i++) {
    int c = c0 + ty + i * 8;
    int r = r0 + tx;
    outb[(size_t)c * R + r] = (bf16_t)tile[tx][ty + i * 8];
  }
}

// ---------------- rmsnorm1: fp32 row -> bf16 hi/lo pair [t][2048] ----------------
__global__ __launch_bounds__(256) void rmsnorm1_k(const float* __restrict__ hs,
                                                  const float* __restrict__ sc,
                                                  bf16_t* __restrict__ xnH,
                                                  bf16_t* __restrict__ xnL) {
  const int t = blockIdx.x;
  const float* row = hs + (size_t)t * DMOD;
  const int tid = threadIdx.x;
  const int i0 = tid * 8;
  float4 a = *(const float4*)(row + i0);
  float4 b = *(const float4*)(row + i0 + 4);
  float x[8] = {a.x, a.y, a.z, a.w, b.x, b.y, b.z, b.w};
  float ss = 0.f;
#pragma unroll
  for (int j = 0; j < 8; j++) ss += x[j] * x[j];
  ss = wredsum(ss);
  __shared__ float red[4];
  if ((tid & 63) == 0) red[tid >> 6] = ss;
  __syncthreads();
  float rn = rsqrtf((red[0] + red[1] + red[2] + red[3]) * (1.f / 2048.f) + 1e-6f);
#pragma unroll
  for (int j = 0; j < 8; j++) {
    float v = x[j] * rn * sc[i0 + j];
    bf16_t hi = (bf16_t)v;
    bf16_t lo = (bf16_t)(v - (float)hi);
    xnH[(size_t)t * DMOD + i0 + j] = hi;
    xnL[(size_t)t * DMOD + i0 + j] = lo;
  }
}

// ---------------- fused split MFMA GEMM core ----------------
template <class AHI, class ALO>
__device__ __forceinline__ void gemm_split_core(AHI getAh, ALO getAl,
                                                const bf16_t* __restrict__ Bh,
                                                const bf16_t* __restrict__ Bl,
                                                int ldb, int n0, int K, f32x4 acc[4]) {
  __shared__ bf16_t AsH[64][32], AsL[64][32], BsH[64][32], BsL[64][32];
  const int t = threadIdx.x;
  const int wave = t >> 6, lane = t & 63;
  const int m16 = lane & 15, quad = lane >> 4;
  const int sr = t >> 2, sc = (t & 3) << 3;
  const bf16_t* __restrict__ ah = getAh(sr);
  const bf16_t* __restrict__ al = getAl(sr);
  const bf16_t* __restrict__ bh = Bh + (size_t)(n0 + sr) * ldb;
  const bf16_t* __restrict__ bl = Bl + (size_t)(n0 + sr) * ldb;
  for (int k0 = 0; k0 < K; k0 += 32) {
    __syncthreads();
    *(uint4*)(&AsH[sr][sc]) = *(const uint4*)(ah + k0 + sc);
    *(uint4*)(&AsL[sr][sc]) = *(const uint4*)(al + k0 + sc);
    *(uint4*)(&BsH[sr][sc]) = *(const uint4*)(bh + k0 + sc);
    *(uint4*)(&BsL[sr][sc]) = *(const uint4*)(bl + k0 + sc);
    __syncthreads();
    bf16x8 afh = *(const bf16x8*)(&AsH[wave * 16 + m16][quad * 8]);
    bf16x8 afl = *(const bf16x8*)(&AsL[wave * 16 + m16][quad * 8]);
#pragma unroll
    for (int nt = 0; nt < 4; nt++) {
      bf16x8 bfh = *(const bf16x8*)(&BsH[nt * 16 + m16][quad * 8]);
      bf16x8 bfl = *(const bf16x8*)(&BsL[nt * 16 + m16][quad * 8]);
      acc[nt] = __builtin_amdgcn_mfma_f32_16x16x32_bf16(afh, bfh, acc[nt], 0, 0, 0);
      acc[nt] = __builtin_amdgcn_mfma_f32_16x16x32_bf16(afl, bfh, acc[nt], 0, 0, 0);
      acc[nt] = __builtin_amdgcn_mfma_f32_16x16x32_bf16(afh, bfl, acc[nt], 0, 0, 0);
    }
  }
}

__global__ __launch_bounds__(256) void gemm_split_plain_k(const bf16_t* __restrict__ Ah,
                                                          const bf16_t* __restrict__ Al,
                                                          int lda,
                                                          const bf16_t* __restrict__ Bh,
                                                          const bf16_t* __restrict__ Bl,
                                                          int ldb, int K,
                                                          float* __restrict__ C, int ldc) {
  const int m0 = blockIdx.y * 64, n0 = blockIdx.x * 64;
  f32x4 zz = {0.f, 0.f, 0.f, 0.f};
  f32x4 acc[4] = {zz, zz, zz, zz};
  gemm_split_core([=](int r) { return Ah + (size_t)(m0 + r) * lda; },
                  [=](int r) { return Al + (size_t)(m0 + r) * lda; },
                  Bh, Bl, ldb, n0, K, acc);
  const int t = threadIdx.x, wave = t >> 6, lane = t & 63;
  const int m16 = lane & 15, quad = lane >> 4;
  const int mb = m0 + wave * 16 + quad * 4;
  const int nb = n0 + m16;
#pragma unroll
  for (int nt = 0; nt < 4; nt++)
#pragma unroll
    for (int r = 0; r < 4; r++)
      C[(size_t)(mb + r) * ldc + nb + nt * 16] = acc[nt][r];
}

__global__ __launch_bounds__(256) void gemm_split_resid_k(const bf16_t* __restrict__ Ah,
                                                          const bf16_t* __restrict__ Al,
                                                          int lda,
                                                          const bf16_t* __restrict__ Bh,
                                                          const bf16_t* __restrict__ Bl,
                                                          int ldb, int K,
                                                          const float* __restrict__ resid,
                                                          float* __restrict__ C, int ldc) {
  const int m0 = blockIdx.y * 64, n0 = blockIdx.x * 64;
  f32x4 zz = {0.f, 0.f, 0.f, 0.f};
  f32x4 acc[4] = {zz, zz, zz, zz};
  gemm_split_core([=](int r) { return Ah + (size_t)(m0 + r) * lda; },
                  [=](int r) { return Al + (size_t)(m0 + r) * lda; },
                  Bh, Bl, ldb, n0, K, acc);
  const int t = threadIdx.x, wave = t >> 6, lane = t & 63;
  const int m16 = lane & 15, quad = lane >> 4;
  const int mb = m0 + wave * 16 + quad * 4;
  const int nb = n0 + m16;
#pragma unroll
  for (int nt = 0; nt < 4; nt++)
#pragma unroll
    for (int r = 0; r < 4; r++) {
      size_t idx = (size_t)(mb + r) * ldc + nb + nt * 16;
      C[idx] = acc[nt][r] + resid[idx];
    }
}

// ---------------- plain MFMA GEMM core (MoE, bf16 single) ----------------
template <class AROW>
__device__ __forceinline__ void gemm_core(AROW getA, const bf16_t* __restrict__ Bt, int ldb,
                                          int n0, int K, f32x4 acc[4]) {
  __shared__ bf16_t As[64][32];
  __shared__ bf16_t Bs[64][32];
  const int t = threadIdx.x;
  const int wave = t >> 6, lane = t & 63;
  const int m16 = lane & 15, quad = lane >> 4;
  const int sr = t >> 2, sc = (t & 3) << 3;
  const bf16_t* __restrict__ arow = getA(sr);
  const bf16_t* __restrict__ brow = Bt + (size_t)(n0 + sr) * ldb;
  for (int k0 = 0; k0 < K; k0 += 32) {
    __syncthreads();
    *(uint4*)(&As[sr][sc]) = *(const uint4*)(arow + k0 + sc);
    *(uint4*)(&Bs[sr][sc]) = *(const uint4*)(brow + k0 + sc);
    __syncthreads();
    bf16x8 af = *(const bf16x8*)(&As[wave * 16 + m16][quad * 8]);
#pragma unroll
    for (int nt = 0; nt < 4; nt++) {
      bf16x8 bfr = *(const bf16x8*)(&Bs[nt * 16 + m16][quad * 8]);
      acc[nt] = __builtin_amdgcn_mfma_f32_16x16x32_bf16(af, bfr, acc[nt], 0, 0, 0);
    }
  }
}

// ---------------- qk-norm + rope, IN-PLACE on fp32 qkv ----------------
__global__ __launch_bounds__(128) void qknorm_rope_k(float* __restrict__ qkv,
                                                     const float* __restrict__ qsc,
                                                     const float* __restrict__ ksc,
                                                     const float* __restrict__ cosT,
                                                     const float* __restrict__ sinT) {
  const int t = blockIdx.x;
  const int hh = blockIdx.y;  // 0..31 q heads, 32..35 k heads
  const bool isq = hh < NHQ;
  float* ptr = qkv + (size_t)t * NQKVC + (isq ? hh * HD : NQC + (hh - NHQ) * HD);
  const int i = threadIdx.x;
  float x = ptr[i];
  float ss = x * x;
  ss = wredsum(ss);
  __shared__ float red2[2];
  __shared__ float xs[128];
  if ((i & 63) == 0) red2[i >> 6] = ss;
  __syncthreads();
  float rn = rsqrtf((red2[0] + red2[1]) * (1.f / 128.f) + 1e-6f);
  float xn = x * rn * (isq ? qsc[i] : ksc[i]);
  xs[i] = xn;
  __syncthreads();
  int j = i & 63;
  float c = cosT[t * 64 + j];
  float s = sinT[t * 64 + j];
  float rot = (i < 64) ? -xs[i + 64] : xs[i - 64];
  ptr[i] = xn * c + rot * s;
}

// ---------------- MFMA flash attention, 64-row q tiles, full hi/lo split ----------------
// Layouts (HW-verified): A-frag A[m=lane&15][k=quad*8+j]; B-frag Bt[n=lane&15][k=quad*8+j];
// C/D: row=quad*4+reg, col=lane&15.
// QK^T: A=Q[q][d], B=K[kv][d]  -> S rows=q, cols=kv.
// PV:   A=P[q][kv], B=Vt[d][kv] -> O rows=q, cols=d.
// P round-trips C-layout -> LDS -> A-layout; P region overlays the K tile (dead after QK^T).
__global__ __launch_bounds__(256) void attn_mfma_k(const float* __restrict__ qkv,
                                                   bf16_t* __restrict__ attnH,
                                                   bf16_t* __restrict__ attnL) {
  const int qb = blockIdx.x;   // 64-row q tile (0..31)
  const int hh = blockIdx.y;   // q head
  const int hk = hh >> 3;
  __shared__ bf16_t sK[2][64][KSTR];   // [hi/lo][kv=64][d=128]; P overlays after QK^T
  __shared__ bf16_t sV[2][128][VSTR];  // [hi/lo][d=128][kv=64]
  const int t = threadIdx.x;
  const int w = t >> 6, lane = t & 63;
  const int m16 = lane & 15, quad = lane >> 4;
  const float SCALE = 0.08838834764831845f;  // 1/sqrt(128)

  // ---- preload Q fragments (hi/lo) for this wave's 16 q-rows ----
  bf16x8 Qh[4], Ql[4];
  {
    const int qrow = qb * 64 + w * 16 + m16;
    const float* qp = qkv + (size_t)qrow * NQKVC + hh * HD + quad * 8;
#pragma unroll
    for (int kc = 0; kc < 4; kc++) {
      float4 x0 = *(const float4*)(qp + kc * 32);
      float4 x1 = *(const float4*)(qp + kc * 32 + 4);
      float xv[8] = {x0.x, x0.y, x0.z, x0.w, x1.x, x1.y, x1.z, x1.w};
#pragma unroll
      for (int j = 0; j < 8; j++) {
        bf16_t hi = (bf16_t)xv[j];
        Qh[kc][j] = hi;
        Ql[kc][j] = (bf16_t)(xv[j] - (float)hi);
      }
    }
  }
  f32x4 acc[8];
#pragma unroll
  for (int i = 0; i < 8; i++) acc[i] = (f32x4){0.f, 0.f, 0.f, 0.f};
  float mrow[4], lrow[4];
#pragma unroll
  for (int r = 0; r < 4; r++) { mrow[r] = -1e30f; lrow[r] = 0.f; }

  const int Krow = t >> 2;        // staging: 0..63
  const int Kseg = (t & 3) * 32;  // 0/32/64/96
  const int kv0 = (t & 15) * 4;   // V micro-tile col base
  const int d0q = (t >> 4) * 4;   // V micro-tile row base (0..60)
  bf16_t* sP = &sK[0][0][0];      // overlay: per-wave [hi/lo][16][PSTR] at w*2*16*PSTR

  for (int kb = 0; kb <= qb; kb++) {
    __syncthreads();  // prev-tile P/V reads done before restaging
    {  // stage K tile [kv][d] hi/lo
      const float* kp = qkv + (size_t)(kb * 64 + Krow) * NQKVC + NQC + hk * HD + Kseg;
#pragma unroll
      for (int i = 0; i < 4; i++) {
        float4 a = *(const float4*)(kp + i * 8);
        float4 b = *(const float4*)(kp + i * 8 + 4);
        float xv[8] = {a.x, a.y, a.z, a.w, b.x, b.y, b.z, b.w};
        bf16x8 hv, lv;
#pragma unroll
        for (int j = 0; j < 8; j++) {
          bf16_t hi = (bf16_t)xv[j];
          hv[j] = hi;
          lv[j] = (bf16_t)(xv[j] - (float)hi);
        }
        *(bf16x8*)(&sK[0][Krow][Kseg + i * 8]) = hv;
        *(bf16x8*)(&sK[1][Krow][Kseg + i * 8]) = lv;
      }
    }
    {  // stage V tile transposed [d][kv] hi/lo (4x4 register micro-transpose)
#pragma unroll
      for (int half = 0; half < 2; half++) {
        const int d0 = d0q + half * 64;
        float4 vrow[4];
#pragma unroll
        for (int i = 0; i < 4; i++)
          vrow[i] = *(const float4*)(qkv + (size_t)(kb * 64 + kv0 + i) * NQKVC +
                                     NQC + NKVC + hk * HD + d0);
#pragma unroll
        for (int j = 0; j < 4; j++) {
          float x0 = ((const float*)&vrow[0])[j], x1 = ((const float*)&vrow[1])[j];
          float x2 = ((const float*)&vrow[2])[j], x3 = ((const float*)&vrow[3])[j];
          bf16_t h0 = (bf16_t)x0, h1 = (bf16_t)x1, h2 = (bf16_t)x2, h3 = (bf16_t)x3;
          *(bf16x4*)(&sV[0][d0 + j][kv0]) = (bf16x4){h0, h1, h2, h3};
          *(bf16x4*)(&sV[1][d0 + j][kv0]) =
              (bf16x4){(bf16_t)(x0 - (float)h0), (bf16_t)(x1 - (float)h1),
                       (bf16_t)(x2 - (float)h2), (bf16_t)(x3 - (float)h3)};
        }
      }
    }
    __syncthreads();  // staging visible
    // ---- QK^T (split: hi*hi + lo*hi + hi*lo) ----
    f32x4 xs[4];
#pragma unroll
    for (int nt = 0; nt < 4; nt++) {
      f32x4 s = (f32x4){0.f, 0.f, 0.f, 0.f};
      if (kb < qb || nt <= w) {  // wave-uniform: skip fully-masked subtiles
#pragma unroll
        for (int kc = 0; kc < 4; kc++) {
          bf16x8 kh = *(const bf16x8*)(&sK[0][nt * 16 + m16][kc * 32 + quad * 8]);
          bf16x8 kl = *(const bf16x8*)(&sK[1][nt * 16 + m16][kc * 32 + quad * 8]);
          s = __builtin_amdgcn_mfma_f32_16x16x32_bf16(Qh[kc], kh, s, 0, 0, 0);
          s = __builtin_amdgcn_mfma_f32_16x16x32_bf16(Ql[kc], kh, s, 0, 0, 0);
          s = __builtin_amdgcn_mfma_f32_16x16x32_bf16(Qh[kc], kl, s, 0, 0, 0);
        }
      }
      xs[nt] = s;
    }
    __syncthreads();  // all K reads done -> P may overlay sK
    // ---- online softmax (per-row state replicated across the 16 lanes of a quad) ----
    float p[4][4], alpha[4];
#pragma unroll
    for (int r = 0; r < 4; r++) {
      const int rqg = qb * 64 + w * 16 + quad * 4 + r;
      float xr[4];
#pragma unroll
      for (int nt = 0; nt < 4; nt++) {
        int colg = kb * 64 + nt * 16 + m16;
        xr[nt] = (colg <= rqg) ? xs[nt][r] * SCALE : -1e30f;
      }
      float mx = fmaxf(fmaxf(xr[0], xr[1]), fmaxf(xr[2], xr[3]));
#pragma unroll
      for (int off = 1; off < 16; off <<= 1) mx = fmaxf(mx, __shfl_xor(mx, off));
      float mn = fmaxf(mrow[r], mx);
      float al = __expf(mrow[r] - mn);
      float rs = 0.f;
#pragma unroll
      for (int nt = 0; nt < 4; nt++) {
        float pv = __expf(xr[nt] - mn);
        p[nt][r] = pv;
        rs += pv;
      }
#pragma unroll
      for (int off = 1; off < 16; off <<= 1) rs += __shfl_xor(rs, off);
      lrow[r] = lrow[r] * al + rs;
      mrow[r] = mn;
      alpha[r] = al;
    }
#pragma unroll
    for (int dt = 0; dt < 8; dt++)
#pragma unroll
      for (int r = 0; r < 4; r++) acc[dt][r] *= alpha[r];
    // ---- write P (hi/lo) to per-wave overlay region, C-layout -> A-layout ----
    {
      bf16_t* base = sP + (size_t)w * 2 * 16 * PSTR;
#pragma unroll
      for (int nt = 0; nt < 4; nt++)
#pragma unroll
        for (int r = 0; r < 4; r++) {
          float pv = p[nt][r];
          bf16_t hi = (bf16_t)pv;
          base[(quad * 4 + r) * PSTR + nt * 16 + m16] = hi;
          base[16 * PSTR + (quad * 4 + r) * PSTR + nt * 16 + m16] = (bf16_t)(pv - (float)hi);
        }
    }
    // ---- PV (same-wave LDS write->read; lgkmcnt ordering by compiler) ----
    {
      const bf16_t* base = sP + (size_t)w * 2 * 16 * PSTR;
      bf16x8 Ph[2], Pl[2];
#pragma unroll
      for (int kc = 0; kc < 2; kc++) {
        Ph[kc] = *(const bf16x8*)(base + m16 * PSTR + kc * 32 + quad * 8);
        Pl[kc] = *(const bf16x8*)(base + 16 * PSTR + m16 * PSTR + kc * 32 + quad * 8);
      }
#pragma unroll
      for (int dt = 0; dt < 8; dt++)
#pragma unroll
        for (int kc = 0; kc < 2; kc++) {
          bf16x8 vh = *(const bf16x8*)(&sV[0][dt * 16 + m16][kc * 32 + quad * 8]);
          bf16x8 vl = *(const bf16x8*)(&sV[1][dt * 16 + m16][kc * 32 + quad * 8]);
          acc[dt] = __builtin_amdgcn_mfma_f32_16x16x32_bf16(Ph[kc], vh, acc[dt], 0, 0, 0);
          acc[dt] = __builtin_amdgcn_mfma_f32_16x16x32_bf16(Pl[kc], vh, acc[dt], 0, 0, 0);
          acc[dt] = __builtin_amdgcn_mfma_f32_16x16x32_bf16(Ph[kc], vl, acc[dt], 0, 0, 0);
        }
    }
  }
  // ---- epilogue: normalize, split, store ----
#pragma unroll
  for (int r = 0; r < 4; r++) {
    const int tok = qb * 64 + w * 16 + quad * 4 + r;
    const float linv = 1.f / lrow[r];
    const size_t ro = (size_t)tok * NQC + hh * HD;
#pragma unroll
    for (int dt = 0; dt < 8; dt++) {
      float v = acc[dt][r] * linv;
      bf16_t hi = (bf16_t)v;
      attnH[ro + dt * 16 + m16] = hi;
      attnL[ro + dt * 16 + m16] = (bf16_t)(v - (float)hi);
    }
  }
}

// ---------------- rmsnorm2 + router logits (fp32, deterministic) ----------------
__global__ __launch_bounds__(256) void rmsnorm2_router_k(const float* __restrict__ hid,
                                                         const float* __restrict__ sc2,
                                                         const float* __restrict__ rW,
                                                         bf16_t* __restrict__ xf,
                                                         float* __restrict__ rlog) {
  const int t = blockIdx.x;
  const float* row = hid + (size_t)t * DMOD;
  const int tid = threadIdx.x;
  const int i0 = tid * 8;
  float4 a = *(const float4*)(row + i0);
  float4 b = *(const float4*)(row + i0 + 4);
  float x[8] = {a.x, a.y, a.z, a.w, b.x, b.y, b.z, b.w};
  float ss = 0.f;
#pragma unroll
  for (int j = 0; j < 8; j++) ss += x[j] * x[j];
  ss = wredsum(ss);
  __shared__ float red[4];
  if ((tid & 63) == 0) red[tid >> 6] = ss;
  __syncthreads();
  float rn = rsqrtf((red[0] + red[1] + red[2] + red[3]) * (1.f / 2048.f) + 1e-6f);
  float acc[8];
#pragma unroll
  for (int e = 0; e < 8; e++) acc[e] = 0.f;
#pragma unroll
  for (int j = 0; j < 8; j++) {
    float xn = x[j] * rn * sc2[i0 + j];
    xf[(size_t)t * DMOD + i0 + j] = (bf16_t)xn;
    const float* w = rW + (size_t)(i0 + j) * NEXP;
#pragma unroll
    for (int e = 0; e < 8; e++) acc[e] += xn * w[e];
  }
#pragma unroll
  for (int e = 0; e < 8; e++) acc[e] = wredsum(acc[e]);
  __shared__ float wacc[4][8];
  if ((tid & 63) == 0)
#pragma unroll
    for (int e = 0; e < 8; e++) wacc[tid >> 6][e] = acc[e];
  __syncthreads();
  if (tid < 8) rlog[t * NEXP + tid] = wacc[0][tid] + wacc[1][tid] + wacc[2][tid] + wacc[3][tid];
}

// ---------------- top-2 selection + gates; aux_loss == 1.0 analytically ----------------
__global__ void topk_k(const float* __restrict__ rlog, int* __restrict__ sel,
                       float* __restrict__ gates, float* __restrict__ aux) {
  int t = blockIdx.x * 256 + threadIdx.x;
  if (t == 0) aux[0] = 1.0f;
  if (t >= SLEN) return;
  const float* l = rlog + t * NEXP;
  int i1 = 0; float v1 = l[0];
#pragma unroll
  for (int e = 1; e < 8; e++) if (l[e] > v1) { v1 = l[e]; i1 = e; }
  int i2 = -1; float v2 = -1e30f;
#pragma unroll
  for (int e = 0; e < 8; e++) if (e != i1 && l[e] > v2) { v2 = l[e]; i2 = e; }
  float e21 = expf(v2 - v1);
  float inv = 1.f / (1.f + e21);
  sel[t * 2 + 0] = i1;
  sel[t * 2 + 1] = i2;
  gates[t * 2 + 0] = inv;
  gates[t * 2 + 1] = e21 * inv;
}

// ---------------- scatter tokens to per-expert lists ----------------
__global__ void scatter_k(const int* __restrict__ sel, const float* __restrict__ gates,
                          int* __restrict__ cnt, int* __restrict__ tok,
                          float* __restrict__ gateL) {
  int i = blockIdx.x * 256 + threadIdx.x;
  if (i >= SLEN * 2) return;
  int e = sel[i];
  int pos = atomicAdd(&cnt[e], 1);
  tok[e * SLEN + pos] = i >> 1;
  gateL[e * SLEN + pos] = gates[i];
}

// ---------------- MoE up-GEMM (gathered rows, silu+bias epilogue, bf16 out) ----------------
__global__ __launch_bounds__(256) void gemm_up_k(const bf16_t* __restrict__ xf,
                                                 const bf16_t* __restrict__ upWT,
                                                 const int* __restrict__ cnt,
                                                 const int* __restrict__ tok,
                                                 const float* __restrict__ up_b,
                                                 bf16_t* __restrict__ hbuf) {
  const int e = blockIdx.z;
  const int c = cnt[e];
  const int m0 = blockIdx.y * 64;
  if (m0 >= c) return;
  const int n0 = blockIdx.x * 64;
  const int* tokE = tok + e * SLEN;
  const bf16_t* BtE = upWT + (size_t)e * NF * DMOD;
  f32x4 zz = {0.f, 0.f, 0.f, 0.f};
  f32x4 acc[4] = {zz, zz, zz, zz};
  gemm_core([=](int r) {
      int s = m0 + r; if (s >= c) s = c - 1;
      return xf + (size_t)tokE[s] * DMOD;
    }, BtE, DMOD, n0, DMOD, acc);
  const int t = threadIdx.x, wave = t >> 6, lane = t & 63;
  const int m16 = lane & 15, quad = lane >> 4;
  const int mb = m0 + wave * 16 + quad * 4;
  const int nb = n0 + m16;
#pragma unroll
  for (int nt = 0; nt < 4; nt++)
#pragma unroll
    for (int r = 0; r < 4; r++) {
      int slot = mb + r;
      if (slot < c) {
        int n = nb + nt * 16;
        float x = acc[nt][r] + up_b[e * NF + n];
        float v = x / (1.f + __expf(-x));
        hbuf[((size_t)e * SLEN + slot) * NF + n] = (bf16_t)v;
      }
    }
}

// ---------------- MoE down-GEMM (bias + gate, atomicAdd into final hidden) ----------------
__global__ __launch_bounds__(256) void gemm_down_k(const bf16_t* __restrict__ hbuf,
                                                   const bf16_t* __restrict__ downWT,
                                                   const int* __restrict__ cnt,
                                                   const int* __restrict__ tok,
                                                   const float* __restrict__ gateL,
                                                   const float* __restrict__ down_b,
                                                   float* __restrict__ outH) {
  const int e = blockIdx.z;
  const int c = cnt[e];
  const int m0 = blockIdx.y * 64;
  if (m0 >= c) return;
  const int n0 = blockIdx.x * 64;
  const bf16_t* Ah = hbuf + (size_t)e * SLEN * NF;
  const bf16_t* BtE = downWT + (size_t)e * DMOD * NF;
  f32x4 zz = {0.f, 0.f, 0.f, 0.f};
  f32x4 acc[4] = {zz, zz, zz, zz};
  gemm_core([=](int r) { return Ah + (size_t)(m0 + r) * NF; }, BtE, NF, n0, NF, acc);
  const int t = threadIdx.x, wave = t >> 6, lane = t & 63;
  const int m16 = lane & 15, quad = lane >> 4;
  const int mb = m0 + wave * 16 + quad * 4;
  const int nb = n0 + m16;
#pragma unroll
  for (int nt = 0; nt < 4; nt++)
#pragma unroll
    for (int r = 0; r < 4; r++) {
      int slot = mb + r;
      if (slot < c) {
        int n = nb + nt * 16;
        int tk = tok[e * SLEN + slot];
        float g = gateL[e * SLEN + slot];
        atomicAdd(&outH[(size_t)tk * DMOD + n], g * (acc[nt][r] + down_b[e * DMOD + n]));
      }
    }
}

// ---------------- host ----------------
extern "C" void kernel_launch(void* const* d_in, const int* in_sizes, int n_in,
                              void* d_out, int out_size, void* d_ws, size_t ws_size,
                              hipStream_t stream) {
  (void)in_sizes; (void)n_in; (void)out_size;
  const float* hs   = (const float*)d_in[0];
  const float* ln1  = (const float*)d_in[1];
  const float* ln2  = (const float*)d_in[2];
  const float* Wq   = (const float*)d_in[3];
  const float* Wk   = (const float*)d_in[4];
  const float* Wv   = (const float*)d_in[5];
  const float* Wo   = (const float*)d_in[6];
  const float* qns  = (const float*)d_in[7];
  const float* kns  = (const float*)d_in[8];
  const float* rW   = (const float*)d_in[9];
  const float* upW  = (const float*)d_in[10];
  const float* upB  = (const float*)d_in[11];
  const float* dnW  = (const float*)d_in[12];
  const float* dnB  = (const float*)d_in[13];
  float* dout = (float*)d_out;

  // ---- workspace layout with lifetime overlays (total ~135.5 MB) ----
  const size_t NEED = 135431168ull;
  if (ws_size < NEED) return;  // clean failure instead of OOB crash
  char* ws = (char*)d_ws;
  const size_t OA = 0;
  const size_t OB = OA + 41943040ull;
  const size_t OC = OB + 33554432ull;
  const size_t OD = OC + 16777216ull;
  const size_t OE = OD + 41943040ull;

  bf16_t* BqkvH  = (bf16_t*)(ws + OA);
  bf16_t* BqkvL  = (bf16_t*)(ws + OA + 20971520ull);
  bf16_t* attnH  = (bf16_t*)(ws + OA);
  bf16_t* attnL  = (bf16_t*)(ws + OA + 16777216ull);
  bf16_t* upWT   = (bf16_t*)(ws + OA);
  bf16_t* WoH    = (bf16_t*)(ws + OB);
  bf16_t* WoL    = (bf16_t*)(ws + OB + 16777216ull);
  bf16_t* hbuf   = (bf16_t*)(ws + OB);
  bf16_t* xnH    = (bf16_t*)(ws + OC);
  bf16_t* xnL    = (bf16_t*)(ws + OC + 8388608ull);
  bf16_t* xf     = (bf16_t*)(ws + OC);
  float*  qkv    = (float*)(ws + OD);
  bf16_t* downWT = (bf16_t*)(ws + OD);
  float*  cosT   = (float*)(ws + OE);
  float*  sinT   = (float*)(ws + OE + 524288ull);
  int*    sel    = (int*)(ws + OE + 1048576ull);
  float*  gates  = (float*)(ws + OE + 1064960ull);
  int*    cnt    = (int*)(ws + OE + 1081344ull);
  int*    tok    = (int*)(ws + OE + 1082368ull);
  float*  gateL  = (float*)(ws + OE + 1147904ull);

  hipMemsetAsync(cnt, 0, 1024, stream);
  rope_table_k<<<512, 256, 0, stream>>>(cosT, sinT);

  dim3 tb(32, 8);
  transpose_split2_k<<<dim3(128, 64), tb, 0, stream>>>(Wq, BqkvH, BqkvL, 2048, 4096);
  transpose_split2_k<<<dim3(16, 64), tb, 0, stream>>>(Wk, BqkvH + (size_t)4096 * 2048,
                                                      BqkvL + (size_t)4096 * 2048, 2048, 512);
  transpose_split2_k<<<dim3(16, 64), tb, 0, stream>>>(Wv, BqkvH + (size_t)4608 * 2048,
                                                      BqkvL + (size_t)4608 * 2048, 2048, 512);
  transpose_split2_k<<<dim3(64, 128), tb, 0, stream>>>(Wo, WoH, WoL, 4096, 2048);

  rmsnorm1_k<<<2048, 256, 0, stream>>>(hs, ln1, xnH, xnL);
  gemm_split_plain_k<<<dim3(80, 32), 256, 0, stream>>>(xnH, xnL, 2048, BqkvH, BqkvL, 2048,
                                                       2048, qkv, NQKVC);
  qknorm_rope_k<<<dim3(2048, 36), 128, 0, stream>>>(qkv, qns, kns, cosT, sinT);
  attn_mfma_k<<<dim3(32, 32), 256, 0, stream>>>(qkv, attnH, attnL);
  gemm_split_resid_k<<<dim3(32, 32), 256, 0, stream>>>(attnH, attnL, 4096, WoH, WoL, 4096,
                                                       4096, hs, dout, DMOD);

  rmsnorm2_router_k<<<2048, 256, 0, stream>>>(dout, ln2, rW, xf, dout + 4194304);
  topk_k<<<8, 256, 0, stream>>>(dout + 4194304, sel, gates, dout + 4210688);
  scatter_k<<<16, 256, 0, stream>>>(sel, gates, cnt, tok, gateL);

  transpose_plain_k<<<dim3(24, 64, 8), tb, 0, stream>>>(upW, upWT, 2048, 768);
  transpose_plain_k<<<dim3(64, 24, 8), tb, 0, stream>>>(dnW, downWT, 768, 2048);

  gemm_up_k<<<dim3(12, 32, 8), 256, 0, stream>>>(xf, upWT, cnt, tok, upB, hbuf);
  gemm_down_k<<<dim3(32, 32, 8), 256, 0, stream>>>(hbuf, downWT, cnt, tok, gateL, dnB, dout);
}

// Round 6
// 1110.503 us; speedup vs baseline: 2.0785x; 1.0987x over previous
//
#include <hip/hip_runtime.h>
#include <cmath>

typedef __bf16 bf16_t;
typedef __bf16 bf16x8 __attribute__((ext_vector_type(8)));
typedef __bf16 bf16x4 __attribute__((ext_vector_type(4)));
typedef float  f32x4  __attribute__((ext_vector_type(4)));

#define SLEN 2048
#define DMOD 2048
#define NHQ  32
#define NHKV 4
#define HD   128
#define NQC  4096
#define NKVC 512
#define NQKVC 5120
#define NEXP 8
#define NF   768

// LDS strides for attention tiles (see round-4 note: inner dim >= full tile
// extent, stride % 8 == 0 for aligned ds_read_b128).
#define KSTR 136
#define VSTR 72
#define PSTR 72

// ---------------- helpers ----------------
__device__ __forceinline__ float wredsum(float v) {
#pragma unroll
  for (int off = 32; off > 0; off >>= 1) v += __shfl_xor(v, off);
  return v;
}

// async global->LDS, 16 B per lane. LDS dest is wave-uniform base + lane*16
// (HW rule) -> pass a wave-uniform LDS pointer; per-lane global pointers.
__device__ __forceinline__ void gll16(const bf16_t* g, bf16_t* l) {
  __builtin_amdgcn_global_load_lds((const __attribute__((address_space(1))) void*)g,
                                   (__attribute__((address_space(3))) void*)l, 16, 0, 0);
}

// ---------------- rope table (fp64 for accuracy) ----------------
__global__ void rope_table_k(float* __restrict__ cosT, float* __restrict__ sinT) {
  int idx = blockIdx.x * 256 + threadIdx.x;
  if (idx >= SLEN * 64) return;
  int t = idx >> 6, j = idx & 63;
  double inv = exp(-0.2158673524681918 * (double)j);  // ln(1e6)/64
  double ang = (double)t * inv;
  cosT[idx] = (float)cos(ang);
  sinT[idx] = (float)sin(ang);
}

// ---------------- weight transpose: fp32 [R][C] -> bf16 hi/lo pair [C][R] ----------------
__global__ __launch_bounds__(256) void transpose_split2_k(const float* __restrict__ in,
                                                          bf16_t* __restrict__ outH,
                                                          bf16_t* __restrict__ outL,
                                                          int R, int C) {
  __shared__ float tile[32][33];
  int tx = threadIdx.x, ty = threadIdx.y;
  int c0 = blockIdx.x * 32, r0 = blockIdx.y * 32;
#pragma unroll
  for (int i = 0; i < 4; i++)
    tile[ty + i * 8][tx] = in[(size_t)(r0 + ty + i * 8) * C + c0 + tx];
  __syncthreads();
#pragma unroll
  for (int i = 0; i < 4; i++) {
    int c = c0 + ty + i * 8;
    int r = r0 + tx;
    float w = tile[tx][ty + i * 8];
    bf16_t hi = (bf16_t)w;
    bf16_t lo = (bf16_t)(w - (float)hi);
    size_t o = (size_t)c * R + r;
    outH[o] = hi;
    outL[o] = lo;
  }
}

// ---------------- plain transpose: fp32 [b][R][C] -> bf16 [b][C][R] ----------------
__global__ __launch_bounds__(256) void transpose_plain_k(const float* __restrict__ in,
                                                         bf16_t* __restrict__ out,
                                                         int R, int C) {
  __shared__ float tile[32][33];
  int b = blockIdx.z;
  const float* inb = in + (size_t)b * R * C;
  bf16_t* outb = out + (size_t)b * R * C;
  int tx = threadIdx.x, ty = threadIdx.y;
  int c0 = blockIdx.x * 32, r0 = blockIdx.y * 32;
#pragma unroll
  for (int i = 0; i < 4; i++)
    tile[ty + i * 8][tx] = inb[(size_t)(r0 + ty + i * 8) * C + c0 + tx];
  __syncthreads();
#pragma unroll
  for (int i = 0; i < 4; i++) {
    int c = c0 + ty + i * 8;
    int r = r0 + tx;
    outb[(size_t)c * R + r] = (bf16_t)tile[tx][ty + i * 8];
  }
}

// ---------------- rmsnorm1: fp32 row -> bf16 hi/lo pair [t][2048] ----------------
__global__ __launch_bounds__(256) void rmsnorm1_k(const float* __restrict__ hs,
                                                  const float* __restrict__ sc,
                                                  bf16_t* __restrict__ xnH,
                                                  bf16_t* __restrict__ xnL) {
  const int t = blockIdx.x;
  const float* row = hs + (size_t)t * DMOD;
  const int tid = threadIdx.x;
  const int i0 = tid * 8;
  float4 a = *(const float4*)(row + i0);
  float4 b = *(const float4*)(row + i0 + 4);
  float x[8] = {a.x, a.y, a.z, a.w, b.x, b.y, b.z, b.w};
  float ss = 0.f;
#pragma unroll
  for (int j = 0; j < 8; j++) ss += x[j] * x[j];
  ss = wredsum(ss);
  __shared__ float red[4];
  if ((tid & 63) == 0) red[tid >> 6] = ss;
  __syncthreads();
  float rn = rsqrtf((red[0] + red[1] + red[2] + red[3]) * (1.f / 2048.f) + 1e-6f);
#pragma unroll
  for (int j = 0; j < 8; j++) {
    float v = x[j] * rn * sc[i0 + j];
    bf16_t hi = (bf16_t)v;
    bf16_t lo = (bf16_t)(v - (float)hi);
    xnH[(size_t)t * DMOD + i0 + j] = hi;
    xnL[(size_t)t * DMOD + i0 + j] = lo;
  }
}

// ---------------- 128x128 split MFMA GEMM (m97 structure + hi/lo split) ----------------
// 4 waves in 2x2; each wave owns a 64x64 quadrant = 4x4 MFMA tiles.
// Staging via global_load_lds width=16, tiles [128][32] bf16, NO padding
// (global_load_lds dest = wave-uniform base + lane*16; mapping verified:
//  t=w*64+l -> row=issue*64+(t>>2), col=(t&3)*8  <=>  byte off issue*4096+w*1024+l*16).
template <bool RESID>
__global__ __launch_bounds__(256) void gemm_split128_k(const bf16_t* __restrict__ Ah,
                                                       const bf16_t* __restrict__ Al,
                                                       int lda,
                                                       const bf16_t* __restrict__ Bh,
                                                       const bf16_t* __restrict__ Bl,
                                                       int ldb, int K,
                                                       const float* __restrict__ resid,
                                                       float* __restrict__ C, int ldc) {
  __shared__ bf16_t AsH[128][32], AsL[128][32], BsH[128][32], BsL[128][32];
  const int t = threadIdx.x;
  const int w = t >> 6, lane = t & 63;
  const int m16 = lane & 15, quad = lane >> 4;
  const int m0 = blockIdx.y * 128, n0 = blockIdx.x * 128;
  const int wm = (w & 1) * 64, wn = (w >> 1) * 64;
  f32x4 acc[4][4];
#pragma unroll
  for (int i = 0; i < 4; i++)
#pragma unroll
    for (int j = 0; j < 4; j++) acc[i][j] = (f32x4){0.f, 0.f, 0.f, 0.f};

  const int srow = t >> 2;         // 0..63
  const int scol = (t & 3) * 8;    // element col within BK=32
  const int lw = w * 512;          // wave-uniform LDS elem offset
  const bf16_t* gAh0 = Ah + (size_t)(m0 + srow) * lda + scol;
  const bf16_t* gAh1 = Ah + (size_t)(m0 + 64 + srow) * lda + scol;
  const bf16_t* gAl0 = Al + (size_t)(m0 + srow) * lda + scol;
  const bf16_t* gAl1 = Al + (size_t)(m0 + 64 + srow) * lda + scol;
  const bf16_t* gBh0 = Bh + (size_t)(n0 + srow) * ldb + scol;
  const bf16_t* gBh1 = Bh + (size_t)(n0 + 64 + srow) * ldb + scol;
  const bf16_t* gBl0 = Bl + (size_t)(n0 + srow) * ldb + scol;
  const bf16_t* gBl1 = Bl + (size_t)(n0 + 64 + srow) * ldb + scol;

  for (int k0 = 0; k0 < K; k0 += 32) {
    __syncthreads();
    gll16(gAh0 + k0, &AsH[0][0] + lw);
    gll16(gAh1 + k0, &AsH[0][0] + 2048 + lw);
    gll16(gAl0 + k0, &AsL[0][0] + lw);
    gll16(gAl1 + k0, &AsL[0][0] + 2048 + lw);
    gll16(gBh0 + k0, &BsH[0][0] + lw);
    gll16(gBh1 + k0, &BsH[0][0] + 2048 + lw);
    gll16(gBl0 + k0, &BsL[0][0] + lw);
    gll16(gBl1 + k0, &BsL[0][0] + 2048 + lw);
    __syncthreads();
    bf16x8 a_h[4], a_l[4];
#pragma unroll
    for (int mt = 0; mt < 4; mt++) {
      a_h[mt] = *(const bf16x8*)(&AsH[wm + mt * 16 + m16][quad * 8]);
      a_l[mt] = *(const bf16x8*)(&AsL[wm + mt * 16 + m16][quad * 8]);
    }
#pragma unroll
    for (int nt = 0; nt < 4; nt++) {
      bf16x8 b_h = *(const bf16x8*)(&BsH[wn + nt * 16 + m16][quad * 8]);
      bf16x8 b_l = *(const bf16x8*)(&BsL[wn + nt * 16 + m16][quad * 8]);
#pragma unroll
      for (int mt = 0; mt < 4; mt++) {
        acc[mt][nt] = __builtin_amdgcn_mfma_f32_16x16x32_bf16(a_h[mt], b_h, acc[mt][nt], 0, 0, 0);
        acc[mt][nt] = __builtin_amdgcn_mfma_f32_16x16x32_bf16(a_l[mt], b_h, acc[mt][nt], 0, 0, 0);
        acc[mt][nt] = __builtin_amdgcn_mfma_f32_16x16x32_bf16(a_h[mt], b_l, acc[mt][nt], 0, 0, 0);
      }
    }
  }
  // epilogue: C row = m0+wm+mt*16+quad*4+r, col = n0+wn+nt*16+m16
#pragma unroll
  for (int mt = 0; mt < 4; mt++)
#pragma unroll
    for (int r = 0; r < 4; r++) {
      const size_t row = m0 + wm + mt * 16 + quad * 4 + r;
#pragma unroll
      for (int nt = 0; nt < 4; nt++) {
        const size_t idx = row * ldc + n0 + wn + nt * 16 + m16;
        if (RESID) C[idx] = acc[mt][nt][r] + resid[idx];
        else       C[idx] = acc[mt][nt][r];
      }
    }
}

// ---------------- plain MFMA GEMM core (MoE, bf16 single) ----------------
template <class AROW>
__device__ __forceinline__ void gemm_core(AROW getA, const bf16_t* __restrict__ Bt, int ldb,
                                          int n0, int K, f32x4 acc[4]) {
  __shared__ bf16_t As[64][32];
  __shared__ bf16_t Bs[64][32];
  const int t = threadIdx.x;
  const int wave = t >> 6, lane = t & 63;
  const int m16 = lane & 15, quad = lane >> 4;
  const int sr = t >> 2, sc = (t & 3) << 3;
  const bf16_t* __restrict__ arow = getA(sr);
  const bf16_t* __restrict__ brow = Bt + (size_t)(n0 + sr) * ldb;
  for (int k0 = 0; k0 < K; k0 += 32) {
    __syncthreads();
    *(uint4*)(&As[sr][sc]) = *(const uint4*)(arow + k0 + sc);
    *(uint4*)(&Bs[sr][sc]) = *(const uint4*)(brow + k0 + sc);
    __syncthreads();
    bf16x8 af = *(const bf16x8*)(&As[wave * 16 + m16][quad * 8]);
#pragma unroll
    for (int nt = 0; nt < 4; nt++) {
      bf16x8 bfr = *(const bf16x8*)(&Bs[nt * 16 + m16][quad * 8]);
      acc[nt] = __builtin_amdgcn_mfma_f32_16x16x32_bf16(af, bfr, acc[nt], 0, 0, 0);
    }
  }
}

// ---------------- qk-norm + rope, IN-PLACE on fp32 qkv ----------------
__global__ __launch_bounds__(128) void qknorm_rope_k(float* __restrict__ qkv,
                                                     const float* __restrict__ qsc,
                                                     const float* __restrict__ ksc,
                                                     const float* __restrict__ cosT,
                                                     const float* __restrict__ sinT) {
  const int t = blockIdx.x;
  const int hh = blockIdx.y;  // 0..31 q heads, 32..35 k heads
  const bool isq = hh < NHQ;
  float* ptr = qkv + (size_t)t * NQKVC + (isq ? hh * HD : NQC + (hh - NHQ) * HD);
  const int i = threadIdx.x;
  float x = ptr[i];
  float ss = x * x;
  ss = wredsum(ss);
  __shared__ float red2[2];
  __shared__ float xs[128];
  if ((i & 63) == 0) red2[i >> 6] = ss;
  __syncthreads();
  float rn = rsqrtf((red2[0] + red2[1]) * (1.f / 128.f) + 1e-6f);
  float xn = x * rn * (isq ? qsc[i] : ksc[i]);
  xs[i] = xn;
  __syncthreads();
  int j = i & 63;
  float c = cosT[t * 64 + j];
  float s = sinT[t * 64 + j];
  float rot = (i < 64) ? -xs[i + 64] : xs[i - 64];
  ptr[i] = xn * c + rot * s;
}

// ---------------- MFMA flash attention, 64-row q tiles, full hi/lo split ----------------
__global__ __launch_bounds__(256) void attn_mfma_k(const float* __restrict__ qkv,
                                                   bf16_t* __restrict__ attnH,
                                                   bf16_t* __restrict__ attnL) {
  const int qb = blockIdx.x;   // 64-row q tile (0..31)
  const int hh = blockIdx.y;   // q head
  const int hk = hh >> 3;
  __shared__ bf16_t sK[2][64][KSTR];   // [hi/lo][kv=64][d=128]; P overlays after QK^T
  __shared__ bf16_t sV[2][128][VSTR];  // [hi/lo][d=128][kv=64]
  const int t = threadIdx.x;
  const int w = t >> 6, lane = t & 63;
  const int m16 = lane & 15, quad = lane >> 4;
  const float SCALE = 0.08838834764831845f;  // 1/sqrt(128)

  bf16x8 Qh[4], Ql[4];
  {
    const int qrow = qb * 64 + w * 16 + m16;
    const float* qp = qkv + (size_t)qrow * NQKVC + hh * HD + quad * 8;
#pragma unroll
    for (int kc = 0; kc < 4; kc++) {
      float4 x0 = *(const float4*)(qp + kc * 32);
      float4 x1 = *(const float4*)(qp + kc * 32 + 4);
      float xv[8] = {x0.x, x0.y, x0.z, x0.w, x1.x, x1.y, x1.z, x1.w};
#pragma unroll
      for (int j = 0; j < 8; j++) {
        bf16_t hi = (bf16_t)xv[j];
        Qh[kc][j] = hi;
        Ql[kc][j] = (bf16_t)(xv[j] - (float)hi);
      }
    }
  }
  f32x4 acc[8];
#pragma unroll
  for (int i = 0; i < 8; i++) acc[i] = (f32x4){0.f, 0.f, 0.f, 0.f};
  float mrow[4], lrow[4];
#pragma unroll
  for (int r = 0; r < 4; r++) { mrow[r] = -1e30f; lrow[r] = 0.f; }

  const int Krow = t >> 2;        // staging: 0..63
  const int Kseg = (t & 3) * 32;  // 0/32/64/96
  const int kv0 = (t & 15) * 4;   // V micro-tile col base
  const int d0q = (t >> 4) * 4;   // V micro-tile row base (0..60)
  bf16_t* sP = &sK[0][0][0];      // overlay: per-wave [hi/lo][16][PSTR]

  for (int kb = 0; kb <= qb; kb++) {
    __syncthreads();
    {  // stage K tile [kv][d] hi/lo
      const float* kp = qkv + (size_t)(kb * 64 + Krow) * NQKVC + NQC + hk * HD + Kseg;
#pragma unroll
      for (int i = 0; i < 4; i++) {
        float4 a = *(const float4*)(kp + i * 8);
        float4 b = *(const float4*)(kp + i * 8 + 4);
        float xv[8] = {a.x, a.y, a.z, a.w, b.x, b.y, b.z, b.w};
        bf16x8 hv, lv;
#pragma unroll
        for (int j = 0; j < 8; j++) {
          bf16_t hi = (bf16_t)xv[j];
          hv[j] = hi;
          lv[j] = (bf16_t)(xv[j] - (float)hi);
        }
        *(bf16x8*)(&sK[0][Krow][Kseg + i * 8]) = hv;
        *(bf16x8*)(&sK[1][Krow][Kseg + i * 8]) = lv;
      }
    }
    {  // stage V tile transposed [d][kv] hi/lo
#pragma unroll
      for (int half = 0; half < 2; half++) {
        const int d0 = d0q + half * 64;
        float4 vrow[4];
#pragma unroll
        for (int i = 0; i < 4; i++)
          vrow[i] = *(const float4*)(qkv + (size_t)(kb * 64 + kv0 + i) * NQKVC +
                                     NQC + NKVC + hk * HD + d0);
#pragma unroll
        for (int j = 0; j < 4; j++) {
          float x0 = ((const float*)&vrow[0])[j], x1 = ((const float*)&vrow[1])[j];
          float x2 = ((const float*)&vrow[2])[j], x3 = ((const float*)&vrow[3])[j];
          bf16_t h0 = (bf16_t)x0, h1 = (bf16_t)x1, h2 = (bf16_t)x2, h3 = (bf16_t)x3;
          *(bf16x4*)(&sV[0][d0 + j][kv0]) = (bf16x4){h0, h1, h2, h3};
          *(bf16x4*)(&sV[1][d0 + j][kv0]) =
              (bf16x4){(bf16_t)(x0 - (float)h0), (bf16_t)(x1 - (float)h1),
                       (bf16_t)(x2 - (float)h2), (bf16_t)(x3 - (float)h3)};
        }
      }
    }
    __syncthreads();
    f32x4 xs[4];
#pragma unroll
    for (int nt = 0; nt < 4; nt++) {
      f32x4 s = (f32x4){0.f, 0.f, 0.f, 0.f};
      if (kb < qb || nt <= w) {
#pragma unroll
        for (int kc = 0; kc < 4; kc++) {
          bf16x8 kh = *(const bf16x8*)(&sK[0][nt * 16 + m16][kc * 32 + quad * 8]);
          bf16x8 kl = *(const bf16x8*)(&sK[1][nt * 16 + m16][kc * 32 + quad * 8]);
          s = __builtin_amdgcn_mfma_f32_16x16x32_bf16(Qh[kc], kh, s, 0, 0, 0);
          s = __builtin_amdgcn_mfma_f32_16x16x32_bf16(Ql[kc], kh, s, 0, 0, 0);
          s = __builtin_amdgcn_mfma_f32_16x16x32_bf16(Qh[kc], kl, s, 0, 0, 0);
        }
      }
      xs[nt] = s;
    }
    __syncthreads();
    float p[4][4], alpha[4];
#pragma unroll
    for (int r = 0; r < 4; r++) {
      const int rqg = qb * 64 + w * 16 + quad * 4 + r;
      float xr[4];
#pragma unroll
      for (int nt = 0; nt < 4; nt++) {
        int colg = kb * 64 + nt * 16 + m16;
        xr[nt] = (colg <= rqg) ? xs[nt][r] * SCALE : -1e30f;
      }
      float mx = fmaxf(fmaxf(xr[0], xr[1]), fmaxf(xr[2], xr[3]));
#pragma unroll
      for (int off = 1; off < 16; off <<= 1) mx = fmaxf(mx, __shfl_xor(mx, off));
      float mn = fmaxf(mrow[r], mx);
      float al = __expf(mrow[r] - mn);
      float rs = 0.f;
#pragma unroll
      for (int nt = 0; nt < 4; nt++) {
        float pv = __expf(xr[nt] - mn);
        p[nt][r] = pv;
        rs += pv;
      }
#pragma unroll
      for (int off = 1; off < 16; off <<= 1) rs += __shfl_xor(rs, off);
      lrow[r] = lrow[r] * al + rs;
      mrow[r] = mn;
      alpha[r] = al;
    }
#pragma unroll
    for (int dt = 0; dt < 8; dt++)
#pragma unroll
      for (int r = 0; r < 4; r++) acc[dt][r] *= alpha[r];
    {
      bf16_t* base = sP + (size_t)w * 2 * 16 * PSTR;
#pragma unroll
      for (int nt = 0; nt < 4; nt++)
#pragma unroll
        for (int r = 0; r < 4; r++) {
          float pv = p[nt][r];
          bf16_t hi = (bf16_t)pv;
          base[(quad * 4 + r) * PSTR + nt * 16 + m16] = hi;
          base[16 * PSTR + (quad * 4 + r) * PSTR + nt * 16 + m16] = (bf16_t)(pv - (float)hi);
        }
    }
    {
      const bf16_t* base = sP + (size_t)w * 2 * 16 * PSTR;
      bf16x8 Ph[2], Pl[2];
#pragma unroll
      for (int kc = 0; kc < 2; kc++) {
        Ph[kc] = *(const bf16x8*)(base + m16 * PSTR + kc * 32 + quad * 8);
        Pl[kc] = *(const bf16x8*)(base + 16 * PSTR + m16 * PSTR + kc * 32 + quad * 8);
      }
#pragma unroll
      for (int dt = 0; dt < 8; dt++)
#pragma unroll
        for (int kc = 0; kc < 2; kc++) {
          bf16x8 vh = *(const bf16x8*)(&sV[0][dt * 16 + m16][kc * 32 + quad * 8]);
          bf16x8 vl = *(const bf16x8*)(&sV[1][dt * 16 + m16][kc * 32 + quad * 8]);
          acc[dt] = __builtin_amdgcn_mfma_f32_16x16x32_bf16(Ph[kc], vh, acc[dt], 0, 0, 0);
          acc[dt] = __builtin_amdgcn_mfma_f32_16x16x32_bf16(Pl[kc], vh, acc[dt], 0, 0, 0);
          acc[dt] = __builtin_amdgcn_mfma_f32_16x16x32_bf16(Ph[kc], vl, acc[dt], 0, 0, 0);
        }
    }
  }
#pragma unroll
  for (int r = 0; r < 4; r++) {
    const int tok = qb * 64 + w * 16 + quad * 4 + r;
    const float linv = 1.f / lrow[r];
    const size_t ro = (size_t)tok * NQC + hh * HD;
#pragma unroll
    for (int dt = 0; dt < 8; dt++) {
      float v = acc[dt][r] * linv;
      bf16_t hi = (bf16_t)v;
      attnH[ro + dt * 16 + m16] = hi;
      attnL[ro + dt * 16 + m16] = (bf16_t)(v - (float)hi);
    }
  }
}

// ---------------- rmsnorm2 + router logits (fp32, deterministic) ----------------
__global__ __launch_bounds__(256) void rmsnorm2_router_k(const float* __restrict__ hid,
                                                         const float* __restrict__ sc2,
                                                         const float* __restrict__ rW,
                                                         bf16_t* __restrict__ xf,
                                                         float* __restrict__ rlog) {
  const int t = blockIdx.x;
  const float* row = hid + (size_t)t * DMOD;
  const int tid = threadIdx.x;
  const int i0 = tid * 8;
  float4 a = *(const float4*)(row + i0);
  float4 b = *(const float4*)(row + i0 + 4);
  float x[8] = {a.x, a.y, a.z, a.w, b.x, b.y, b.z, b.w};
  float ss = 0.f;
#pragma unroll
  for (int j = 0; j < 8; j++) ss += x[j] * x[j];
  ss = wredsum(ss);
  __shared__ float red[4];
  if ((tid & 63) == 0) red[tid >> 6] = ss;
  __syncthreads();
  float rn = rsqrtf((red[0] + red[1] + red[2] + red[3]) * (1.f / 2048.f) + 1e-6f);
  float acc[8];
#pragma unroll
  for (int e = 0; e < 8; e++) acc[e] = 0.f;
#pragma unroll
  for (int j = 0; j < 8; j++) {
    float xn = x[j] * rn * sc2[i0 + j];
    xf[(size_t)t * DMOD + i0 + j] = (bf16_t)xn;
    const float* w = rW + (size_t)(i0 + j) * NEXP;
#pragma unroll
    for (int e = 0; e < 8; e++) acc[e] += xn * w[e];
  }
#pragma unroll
  for (int e = 0; e < 8; e++) acc[e] = wredsum(acc[e]);
  __shared__ float wacc[4][8];
  if ((tid & 63) == 0)
#pragma unroll
    for (int e = 0; e < 8; e++) wacc[tid >> 6][e] = acc[e];
  __syncthreads();
  if (tid < 8) rlog[t * NEXP + tid] = wacc[0][tid] + wacc[1][tid] + wacc[2][tid] + wacc[3][tid];
}

// ---------------- top-2 selection + gates; aux_loss == 1.0 analytically ----------------
__global__ void topk_k(const float* __restrict__ rlog, int* __restrict__ sel,
                       float* __restrict__ gates, float* __restrict__ aux) {
  int t = blockIdx.x * 256 + threadIdx.x;
  if (t == 0) aux[0] = 1.0f;
  if (t >= SLEN) return;
  const float* l = rlog + t * NEXP;
  int i1 = 0; float v1 = l[0];
#pragma unroll
  for (int e = 1; e < 8; e++) if (l[e] > v1) { v1 = l[e]; i1 = e; }
  int i2 = -1; float v2 = -1e30f;
#pragma unroll
  for (int e = 0; e < 8; e++) if (e != i1 && l[e] > v2) { v2 = l[e]; i2 = e; }
  float e21 = expf(v2 - v1);
  float inv = 1.f / (1.f + e21);
  sel[t * 2 + 0] = i1;
  sel[t * 2 + 1] = i2;
  gates[t * 2 + 0] = inv;
  gates[t * 2 + 1] = e21 * inv;
}

// ---------------- scatter tokens to per-expert lists ----------------
__global__ void scatter_k(const int* __restrict__ sel, const float* __restrict__ gates,
                          int* __restrict__ cnt, int* __restrict__ tok,
                          float* __restrict__ gateL) {
  int i = blockIdx.x * 256 + threadIdx.x;
  if (i >= SLEN * 2) return;
  int e = sel[i];
  int pos = atomicAdd(&cnt[e], 1);
  tok[e * SLEN + pos] = i >> 1;
  gateL[e * SLEN + pos] = gates[i];
}

// ---------------- MoE up-GEMM (gathered rows, silu+bias epilogue, bf16 out) ----------------
__global__ __launch_bounds__(256) void gemm_up_k(const bf16_t* __restrict__ xf,
                                                 const bf16_t* __restrict__ upWT,
                                                 const int* __restrict__ cnt,
                                                 const int* __restrict__ tok,
                                                 const float* __restrict__ up_b,
                                                 bf16_t* __restrict__ hbuf) {
  const int e = blockIdx.z;
  const int c = cnt[e];
  const int m0 = blockIdx.y * 64;
  if (m0 >= c) return;
  const int n0 = blockIdx.x * 64;
  const int* tokE = tok + e * SLEN;
  const bf16_t* BtE = upWT + (size_t)e * NF * DMOD;
  f32x4 zz = {0.f, 0.f, 0.f, 0.f};
  f32x4 acc[4] = {zz, zz, zz, zz};
  gemm_core([=](int r) {
      int s = m0 + r; if (s >= c) s = c - 1;
      return xf + (size_t)tokE[s] * DMOD;
    }, BtE, DMOD, n0, DMOD, acc);
  const int t = threadIdx.x, wave = t >> 6, lane = t & 63;
  const int m16 = lane & 15, quad = lane >> 4;
  const int mb = m0 + wave * 16 + quad * 4;
  const int nb = n0 + m16;
#pragma unroll
  for (int nt = 0; nt < 4; nt++)
#pragma unroll
    for (int r = 0; r < 4; r++) {
      int slot = mb + r;
      if (slot < c) {
        int n = nb + nt * 16;
        float x = acc[nt][r] + up_b[e * NF + n];
        float v = x / (1.f + __expf(-x));
        hbuf[((size_t)e * SLEN + slot) * NF + n] = (bf16_t)v;
      }
    }
}

// ---------------- MoE down-GEMM (bias + gate, atomicAdd into final hidden) ----------------
__global__ __launch_bounds__(256) void gemm_down_k(const bf16_t* __restrict__ hbuf,
                                                   const bf16_t* __restrict__ downWT,
                                                   const int* __restrict__ cnt,
                                                   const int* __restrict__ tok,
                                                   const float* __restrict__ gateL,
                                                   const float* __restrict__ down_b,
                                                   float* __restrict__ outH) {
  const int e = blockIdx.z;
  const int c = cnt[e];
  const int m0 = blockIdx.y * 64;
  if (m0 >= c) return;
  const int n0 = blockIdx.x * 64;
  const bf16_t* Ah = hbuf + (size_t)e * SLEN * NF;
  const bf16_t* BtE = downWT + (size_t)e * DMOD * NF;
  f32x4 zz = {0.f, 0.f, 0.f, 0.f};
  f32x4 acc[4] = {zz, zz, zz, zz};
  gemm_core([=](int r) { return Ah + (size_t)(m0 + r) * NF; }, BtE, NF, n0, NF, acc);
  const int t = threadIdx.x, wave = t >> 6, lane = t & 63;
  const int m16 = lane & 15, quad = lane >> 4;
  const int mb = m0 + wave * 16 + quad * 4;
  const int nb = n0 + m16;
#pragma unroll
  for (int nt = 0; nt < 4; nt++)
#pragma unroll
    for (int r = 0; r < 4; r++) {
      int slot = mb + r;
      if (slot < c) {
        int n = nb + nt * 16;
        int tk = tok[e * SLEN + slot];
        float g = gateL[e * SLEN + slot];
        atomicAdd(&outH[(size_t)tk * DMOD + n], g * (acc[nt][r] + down_b[e * DMOD + n]));
      }
    }
}

// ---------------- host ----------------
extern "C" void kernel_launch(void* const* d_in, const int* in_sizes, int n_in,
                              void* d_out, int out_size, void* d_ws, size_t ws_size,
                              hipStream_t stream) {
  (void)in_sizes; (void)n_in; (void)out_size;
  const float* hs   = (const float*)d_in[0];
  const float* ln1  = (const float*)d_in[1];
  const float* ln2  = (const float*)d_in[2];
  const float* Wq   = (const float*)d_in[3];
  const float* Wk   = (const float*)d_in[4];
  const float* Wv   = (const float*)d_in[5];
  const float* Wo   = (const float*)d_in[6];
  const float* qns  = (const float*)d_in[7];
  const float* kns  = (const float*)d_in[8];
  const float* rW   = (const float*)d_in[9];
  const float* upW  = (const float*)d_in[10];
  const float* upB  = (const float*)d_in[11];
  const float* dnW  = (const float*)d_in[12];
  const float* dnB  = (const float*)d_in[13];
  float* dout = (float*)d_out;

  // ---- workspace layout with lifetime overlays (total ~135.5 MB) ----
  const size_t NEED = 135431168ull;
  if (ws_size < NEED) return;  // clean failure instead of OOB crash
  char* ws = (char*)d_ws;
  const size_t OA = 0;
  const size_t OB = OA + 41943040ull;
  const size_t OC = OB + 33554432ull;
  const size_t OD = OC + 16777216ull;
  const size_t OE = OD + 41943040ull;

  bf16_t* BqkvH  = (bf16_t*)(ws + OA);
  bf16_t* BqkvL  = (bf16_t*)(ws + OA + 20971520ull);
  bf16_t* attnH  = (bf16_t*)(ws + OA);
  bf16_t* attnL  = (bf16_t*)(ws + OA + 16777216ull);
  bf16_t* upWT   = (bf16_t*)(ws + OA);
  bf16_t* WoH    = (bf16_t*)(ws + OB);
  bf16_t* WoL    = (bf16_t*)(ws + OB + 16777216ull);
  bf16_t* hbuf   = (bf16_t*)(ws + OB);
  bf16_t* xnH    = (bf16_t*)(ws + OC);
  bf16_t* xnL    = (bf16_t*)(ws + OC + 8388608ull);
  bf16_t* xf     = (bf16_t*)(ws + OC);
  float*  qkv    = (float*)(ws + OD);
  bf16_t* downWT = (bf16_t*)(ws + OD);
  float*  cosT   = (float*)(ws + OE);
  float*  sinT   = (float*)(ws + OE + 524288ull);
  int*    sel    = (int*)(ws + OE + 1048576ull);
  float*  gates  = (float*)(ws + OE + 1064960ull);
  int*    cnt    = (int*)(ws + OE + 1081344ull);
  int*    tok    = (int*)(ws + OE + 1082368ull);
  float*  gateL  = (float*)(ws + OE + 1147904ull);

  hipMemsetAsync(cnt, 0, 1024, stream);
  rope_table_k<<<512, 256, 0, stream>>>(cosT, sinT);

  dim3 tb(32, 8);
  transpose_split2_k<<<dim3(128, 64), tb, 0, stream>>>(Wq, BqkvH, BqkvL, 2048, 4096);
  transpose_split2_k<<<dim3(16, 64), tb, 0, stream>>>(Wk, BqkvH + (size_t)4096 * 2048,
                                                      BqkvL + (size_t)4096 * 2048, 2048, 512);
  transpose_split2_k<<<dim3(16, 64), tb, 0, stream>>>(Wv, BqkvH + (size_t)4608 * 2048,
                                                      BqkvL + (size_t)4608 * 2048, 2048, 512);
  transpose_split2_k<<<dim3(64, 128), tb, 0, stream>>>(Wo, WoH, WoL, 4096, 2048);

  rmsnorm1_k<<<2048, 256, 0, stream>>>(hs, ln1, xnH, xnL);
  gemm_split128_k<false><<<dim3(40, 16), 256, 0, stream>>>(xnH, xnL, 2048, BqkvH, BqkvL,
                                                           2048, 2048, nullptr, qkv, NQKVC);
  qknorm_rope_k<<<dim3(2048, 36), 128, 0, stream>>>(qkv, qns, kns, cosT, sinT);
  attn_mfma_k<<<dim3(32, 32), 256, 0, stream>>>(qkv, attnH, attnL);
  gemm_split128_k<true><<<dim3(16, 16), 256, 0, stream>>>(attnH, attnL, 4096, WoH, WoL,
                                                          4096, 4096, hs, dout, DMOD);

  rmsnorm2_router_k<<<2048, 256, 0, stream>>>(dout, ln2, rW, xf, dout + 4194304);
  topk_k<<<8, 256, 0, stream>>>(dout + 4194304, sel, gates, dout + 4210688);
  scatter_k<<<16, 256, 0, stream>>>(sel, gates, cnt, tok, gateL);

  transpose_plain_k<<<dim3(24, 64, 8), tb, 0, stream>>>(upW, upWT, 2048, 768);
  transpose_plain_k<<<dim3(64, 24, 8), tb, 0, stream>>>(dnW, downWT, 768, 2048);

  gemm_up_k<<<dim3(12, 32, 8), 256, 0, stream>>>(xf, upWT, cnt, tok, upB, hbuf);
  gemm_down_k<<<dim3(32, 32, 8), 256, 0, stream>>>(hbuf, downWT, cnt, tok, gateL, dnB, dout);
}